// Round 1
// baseline (196.407 us; speedup 1.0000x reference)
//
#include <hip/hip_runtime.h>

#define LSEQ 1024
#define NH 8
#define NE 64
#define NB 4
#define NTOP 35
#define QKSCALE 0.04419417382415922f   // 1/sqrt(512)

// ---------------------------------------------------------------------------
// Kernel A: circular cross-correlation amplitude^2.
// amp2[bh][l] = sum_e ( sum_t q[b,t,h,e] * k[b,(t-l)&1023,h,e] )^2
// grid = 32 (b,h) * 16 lag-blocks of 64 lags; block = 256 threads.
// Each thread: 8 lags (g=tid>>5, lags l0+8g+lx) x 2 channels (cp=tid&31).
// Rolling k-window in registers: per t-step only 1 new k row per channel.
// ---------------------------------------------------------------------------
__global__ __launch_bounds__(256) void corr_amp_kernel(
    const float* __restrict__ qm, const float* __restrict__ km,
    float* __restrict__ amp2) {
  const int tid = threadIdx.x;
  const int lb  = blockIdx.x & 15;   // lag block
  const int bh  = blockIdx.x >> 4;   // 0..31
  const int l0  = lb << 6;
  const int cp  = tid & 31;          // channel pair -> channels 2cp, 2cp+1
  const int g   = tid >> 5;          // lag group 0..7

  __shared__ float q_tile[64 * 64];
  __shared__ float k_tile[128 * 64];
  __shared__ float red[64 * 33];

  const int b = bh >> 3, h = bh & 7;
  const size_t base = (size_t)b * LSEQ * NH * NE + (size_t)h * NE;

  float acc[8][2];
#pragma unroll
  for (int i = 0; i < 8; ++i) { acc[i][0] = 0.f; acc[i][1] = 0.f; }

  for (int chunk = 0; chunk < 16; ++chunk) {
    const int t0 = chunk << 6;
    __syncthreads();
    // stage q rows t0..t0+63 (64 rows x 64 ch), XOR-swizzled channels
#pragma unroll
    for (int it = 0; it < 8; ++it) {
      int i = (it << 8) + tid;             // 0..2047
      int row = i >> 5;
      int c2  = (i & 31) << 1;
      float2 v = *(const float2*)(qm + base + (size_t)(t0 + row) * (NH * NE) + c2);
      int sw = ((row >> 3) & 15) << 1;
      *(float2*)(&q_tile[(row << 6) + (c2 ^ sw)]) = v;
    }
    // stage k rows: k_tile[r] = k[(t0 - l0 - 63 + r) & 1023], r in [0,128)
    const int kb = t0 - l0 - 63;
#pragma unroll
    for (int it = 0; it < 16; ++it) {
      int i = (it << 8) + tid;             // 0..4095
      int row = i >> 5;
      int c2  = (i & 31) << 1;
      int kr  = (kb + row) & (LSEQ - 1);
      float2 v = *(const float2*)(km + base + (size_t)kr * (NH * NE) + c2);
      int sw = ((row >> 3) & 15) << 1;
      *(float2*)(&k_tile[(row << 6) + (c2 ^ sw)]) = v;
    }
    __syncthreads();

    const int cc = cp << 1;
    for (int tt0 = 0; tt0 < 64; tt0 += 8) {
      float2 qv[8];
#pragma unroll
      for (int dt = 0; dt < 8; ++dt) {
        int tt = tt0 + dt;
        int sw = ((tt >> 3) & 15) << 1;
        qv[dt] = *(const float2*)(&q_tile[(tt << 6) + (cc ^ sw)]);
      }
      // window rows r = tt + 63 - 8g - lx, tt in [tt0,tt0+8), lx in [0,8)
      //   -> 15 consecutive rows starting at rbase = tt0 + 56 - 8g
      float2 kw[15];
      const int rbase = tt0 + 56 - (g << 3);
#pragma unroll
      for (int j = 0; j < 15; ++j) {
        int r = rbase + j;
        int sw = ((r >> 3) & 15) << 1;
        kw[j] = *(const float2*)(&k_tile[(r << 6) + (cc ^ sw)]);
      }
#pragma unroll
      for (int dt = 0; dt < 8; ++dt) {
#pragma unroll
        for (int lx = 0; lx < 8; ++lx) {
          int j = dt + 7 - lx;             // r = rbase + j = tt + 63 - 8g - lx
          acc[lx][0] = fmaf(qv[dt].x, kw[j].x, acc[lx][0]);
          acc[lx][1] = fmaf(qv[dt].y, kw[j].y, acc[lx][1]);
        }
      }
    }
  }

  __syncthreads();
#pragma unroll
  for (int lx = 0; lx < 8; ++lx)
    red[((g << 3) + lx) * 33 + cp] = acc[lx][0] * acc[lx][0] + acc[lx][1] * acc[lx][1];
  __syncthreads();
  if (tid < 64) {
    float s = 0.f;
#pragma unroll
    for (int c = 0; c < 32; ++c) s += red[tid * 33 + c];
    amp2[(size_t)bh * LSEQ + l0 + tid] = s;
  }
}

// ---------------------------------------------------------------------------
// Kernel B: top-35 selection per (b,h) for both branches.
// Branch 0: amp2 from kernel A. Branch 1: row-norm^2 of tf_queries.
// Packed u64 keys (value bits<<32 | (1023-l)) -> lax.top_k tie-break (low idx).
// grid = 32 blocks, block = 256 threads.
// ---------------------------------------------------------------------------
__global__ __launch_bounds__(256) void topk_kernel(
    const float* __restrict__ amp2, const float* __restrict__ tfq,
    int* __restrict__ sel_t, int* __restrict__ sel_tf) {
  __shared__ unsigned long long keys[2 * LSEQ];
  __shared__ unsigned long long wred[4];
  const int tid = threadIdx.x;
  const int bh = blockIdx.x;
  const int b = bh >> 3, h = bh & 7;
  const size_t base = (size_t)b * LSEQ * NH * NE + (size_t)h * NE;

#pragma unroll
  for (int j = 0; j < 4; ++j) {
    int l = tid + (j << 8);
    float a = amp2[(size_t)bh * LSEQ + l];
    keys[l] = ((unsigned long long)__float_as_uint(a) << 32) |
              (unsigned)(LSEQ - 1 - l);
  }
#pragma unroll
  for (int j = 0; j < 4; ++j) {
    int l = tid + (j << 8);
    const float* row = tfq + base + (size_t)l * (NH * NE);
    float s = 0.f;
#pragma unroll
    for (int e = 0; e < NE; e += 4) {
      float4 v = *(const float4*)(row + e);
      s += v.x * v.x + v.y * v.y + v.z * v.z + v.w * v.w;
    }
    keys[LSEQ + l] = ((unsigned long long)__float_as_uint(s) << 32) |
                     (unsigned)(LSEQ - 1 - l);
  }
  __syncthreads();

  for (int arr = 0; arr < 2; ++arr) {
    unsigned long long* kk = keys + arr * LSEQ;
    int* sel = (arr == 0 ? sel_t : sel_tf) + bh * NTOP;
    for (int s = 0; s < NTOP; ++s) {
      unsigned long long m = kk[tid];
#pragma unroll
      for (int j = 1; j < 4; ++j) {
        unsigned long long v = kk[tid + (j << 8)];
        m = (v > m) ? v : m;
      }
#pragma unroll
      for (int off = 32; off > 0; off >>= 1) {
        unsigned long long v = __shfl_down(m, (unsigned)off);
        m = (v > m) ? v : m;
      }
      if ((tid & 63) == 0) wred[tid >> 6] = m;
      __syncthreads();
      if (tid == 0) {
        unsigned long long mm = wred[0];
#pragma unroll
        for (int w = 1; w < 4; ++w) mm = (wred[w] > mm) ? wred[w] : mm;
        int l = (LSEQ - 1) - (int)(mm & 0xffffffffULL);
        sel[s] = l;
        kk[l] = 0ULL;  // remove winner
      }
      __syncthreads();
    }
  }
}

// ---------------------------------------------------------------------------
// Kernel C: scores + per-key softmax (over the 35 selected rows) + mix + PV.
// out[b,h,d,k] = w0(h,k)*sum_n p_t[n]*V[selt_n,d] + w1(h,k)*sum_n p_f[n]*V[self_n,d]
// grid = 32 (b,h) * 8 key-chunks of 128; block = 128 threads (1 key/thread).
// ---------------------------------------------------------------------------
__global__ __launch_bounds__(128) void attn_out_kernel(
    const float* __restrict__ qm, const float* __restrict__ tfq,
    const float* __restrict__ km, const float* __restrict__ vm,
    const float* __restrict__ mixw,
    const int* __restrict__ sel_t, const int* __restrict__ sel_tf,
    float* __restrict__ out) {
  const int tid = threadIdx.x;
  const int kc = blockIdx.x & 7;
  const int bh = blockIdx.x >> 3;
  const int b = bh >> 3, h = bh & 7;
  const size_t base = (size_t)b * LSEQ * NH * NE + (size_t)h * NE;

  __shared__ float qs_t[NTOP * NE];
  __shared__ float qs_f[NTOP * NE];
  __shared__ float vs_t[NTOP * NE];
  __shared__ float vs_f[NTOP * NE];

  for (int i = tid; i < NTOP * NE; i += 128) {
    int n = i >> 6, e = i & 63;
    int lt = sel_t[bh * NTOP + n];
    int lf = sel_tf[bh * NTOP + n];
    qs_t[i] = qm[base + (size_t)lt * (NH * NE) + e];
    qs_f[i] = tfq[base + (size_t)lf * (NH * NE) + e];
    vs_t[i] = vm[base + (size_t)lt * (NH * NE) + e];
    vs_f[i] = vm[base + (size_t)lf * (NH * NE) + e];
  }
  __syncthreads();

  const int kpos = (kc << 7) + tid;
  const float* krow = km + base + (size_t)kpos * (NH * NE);
  const float* frow = tfq + base + (size_t)kpos * (NH * NE);

  float st[NTOP], sf[NTOP];
#pragma unroll
  for (int n = 0; n < NTOP; ++n) { st[n] = 0.f; sf[n] = 0.f; }

  for (int e0 = 0; e0 < NE; e0 += 4) {
    float4 kv = *(const float4*)(krow + e0);
    float4 fv = *(const float4*)(frow + e0);
#pragma unroll
    for (int n = 0; n < NTOP; ++n) {
      float4 qt = *(const float4*)(&qs_t[(n << 6) + e0]);
      st[n] = fmaf(qt.x, kv.x, st[n]);
      st[n] = fmaf(qt.y, kv.y, st[n]);
      st[n] = fmaf(qt.z, kv.z, st[n]);
      st[n] = fmaf(qt.w, kv.w, st[n]);
      float4 qf = *(const float4*)(&qs_f[(n << 6) + e0]);
      sf[n] = fmaf(qf.x, fv.x, sf[n]);
      sf[n] = fmaf(qf.y, fv.y, sf[n]);
      sf[n] = fmaf(qf.z, fv.z, sf[n]);
      sf[n] = fmaf(qf.w, fv.w, sf[n]);
    }
  }

  float mt = -1e30f, mf = -1e30f;
#pragma unroll
  for (int n = 0; n < NTOP; ++n) {
    st[n] *= QKSCALE;
    sf[n] *= QKSCALE;
    mt = fmaxf(mt, st[n]);
    mf = fmaxf(mf, sf[n]);
  }
  float sumt = 0.f, sumf = 0.f;
#pragma unroll
  for (int n = 0; n < NTOP; ++n) {
    st[n] = __expf(st[n] - mt); sumt += st[n];
    sf[n] = __expf(sf[n] - mf); sumf += sf[n];
  }
  const float m0 = mixw[((size_t)h * LSEQ + kpos) * 2 + 0];
  const float m1 = mixw[((size_t)h * LSEQ + kpos) * 2 + 1];
  const float e0w = __expf(m0), e1w = __expf(m1);
  const float inv = 1.f / (e0w + e1w);
  const float ct = e0w * inv / sumt;
  const float cf = e1w * inv / sumf;
#pragma unroll
  for (int n = 0; n < NTOP; ++n) { st[n] *= ct; sf[n] *= cf; }

  float* orow = out + (size_t)bh * NE * LSEQ + kpos;
  for (int d0 = 0; d0 < NE; d0 += 4) {
    float a0 = 0.f, a1 = 0.f, a2 = 0.f, a3 = 0.f;
#pragma unroll
    for (int n = 0; n < NTOP; ++n) {
      float4 vt = *(const float4*)(&vs_t[(n << 6) + d0]);
      float4 vf = *(const float4*)(&vs_f[(n << 6) + d0]);
      a0 = fmaf(st[n], vt.x, a0); a0 = fmaf(sf[n], vf.x, a0);
      a1 = fmaf(st[n], vt.y, a1); a1 = fmaf(sf[n], vf.y, a1);
      a2 = fmaf(st[n], vt.z, a2); a2 = fmaf(sf[n], vf.z, a2);
      a3 = fmaf(st[n], vt.w, a3); a3 = fmaf(sf[n], vf.w, a3);
    }
    orow[(size_t)(d0 + 0) * LSEQ] = a0;
    orow[(size_t)(d0 + 1) * LSEQ] = a1;
    orow[(size_t)(d0 + 2) * LSEQ] = a2;
    orow[(size_t)(d0 + 3) * LSEQ] = a3;
  }
}

// ---------------------------------------------------------------------------
extern "C" void kernel_launch(void* const* d_in, const int* in_sizes, int n_in,
                              void* d_out, int out_size, void* d_ws, size_t ws_size,
                              hipStream_t stream) {
  const float* tfq  = (const float*)d_in[0];
  const float* qm   = (const float*)d_in[1];
  const float* km   = (const float*)d_in[2];
  const float* vm   = (const float*)d_in[3];
  // d_in[4], d_in[5] (weights1_*), d_in[7] (mask), d_in[8] (mode_index):
  // dead code w.r.t. the returned output — skipped.
  const float* mixw = (const float*)d_in[6];

  float* amp2  = (float*)d_ws;                                  // 32*1024 f32
  int*   sel_t = (int*)((char*)d_ws + sizeof(float) * 32 * LSEQ);
  int*   sel_tf = sel_t + 32 * NTOP;
  float* out = (float*)d_out;

  corr_amp_kernel<<<dim3(512), dim3(256), 0, stream>>>(qm, km, amp2);
  topk_kernel<<<dim3(32), dim3(256), 0, stream>>>(amp2, tfq, sel_t, sel_tf);
  attn_out_kernel<<<dim3(256), dim3(128), 0, stream>>>(qm, tfq, km, vm, mixw,
                                                       sel_t, sel_tf, out);
}

// Round 2
// 147.117 us; speedup vs baseline: 1.3350x; 1.3350x over previous
//
#include <hip/hip_runtime.h>

#define LSEQ 1024
#define NH 8
#define NE 64
#define NTOP 35
#define QKSCALE 0.04419417382415922f   // 1/sqrt(512)

typedef unsigned long long u64;

#define ZPAD(i) ((i) + ((i) >> 5))     // pad 1 float2 per 32 -> 1056 slots

// ---------------------------------------------------------------------------
// Zero amp2 (graph-capture-safe init; harness does not re-poison between runs)
// ---------------------------------------------------------------------------
__global__ void zero_kernel(float* __restrict__ p, int n) {
  int i = blockIdx.x * 256 + threadIdx.x;
  if (i < n) p[i] = 0.f;
}

// ---------------------------------------------------------------------------
// Kernel A (FFT): circular cross-correlation amplitude^2 via packed FFTs.
// One block per (bh, channel-pair): z_e = q_e + i*k_e (2 fwd FFTs),
// P_e = Q_e * conj(K_e) extracted via Hermitian partners in bit-rev domain,
// Y = P0 + i*P1 (1 inv FFT) -> y_t = c0_t + i*c1_t -> amp2 += |y_t|^2.
// blockIdx: bh = idx & 31 (fast) so one bh's 32 blocks share an XCD's L2.
// ---------------------------------------------------------------------------
__global__ __launch_bounds__(128) void corr_fft_kernel(
    const float* __restrict__ qm, const float* __restrict__ km,
    float* __restrict__ amp2) {
  const int tid  = threadIdx.x;
  const int bh   = blockIdx.x & 31;
  const int pair = blockIdx.x >> 5;
  const int b = bh >> 3, h = bh & 7;
  const int e0 = pair << 1;
  const size_t base = (size_t)b * (LSEQ * NH * NE) + (size_t)h * NE + e0;

  __shared__ float2 z0[1056];
  __shared__ float2 z1[1056];
  __shared__ float2 tw[512];   // exp(-2*pi*i*j/1024)

  for (int j = tid; j < 512; j += 128) {
    float s, c;
    sincosf(6.283185307179586f * (float)j * (1.0f / 1024.0f), &s, &c);
    tw[j] = make_float2(c, -s);
  }
#pragma unroll
  for (int j = 0; j < 8; ++j) {
    int t = tid + (j << 7);
    float2 qv = *(const float2*)(qm + base + (size_t)t * (NH * NE));
    float2 kv = *(const float2*)(km + base + (size_t)t * (NH * NE));
    z0[ZPAD(t)] = make_float2(qv.x, kv.x);
    z1[ZPAD(t)] = make_float2(qv.y, kv.y);
  }
  __syncthreads();

  // forward DIF: natural in -> bit-reversed out, for z0 and z1
  for (int s = 0; s < 10; ++s) {
    const int hh = 512 >> s;
#pragma unroll
    for (int jj = 0; jj < 4; ++jj) {
      const int bb = tid + (jj << 7);
      const int pos = bb & (hh - 1);
      const int idx0 = ((bb >> (9 - s)) << (10 - s)) | pos;
      const int i0 = ZPAD(idx0), i1 = ZPAD(idx0 + hh);
      const float2 w = tw[pos << s];
      float2 u, v, d;
      u = z0[i0]; v = z0[i1];
      z0[i0] = make_float2(u.x + v.x, u.y + v.y);
      d = make_float2(u.x - v.x, u.y - v.y);
      z0[i1] = make_float2(d.x * w.x - d.y * w.y, d.x * w.y + d.y * w.x);
      u = z1[i0]; v = z1[i1];
      z1[i0] = make_float2(u.x + v.x, u.y + v.y);
      d = make_float2(u.x - v.x, u.y - v.y);
      z1[i1] = make_float2(d.x * w.x - d.y * w.y, d.x * w.y + d.y * w.x);
    }
    __syncthreads();
  }

  // pointwise: P = Q*conj(K) per channel, pack Y = P0 + i*P1 (bit-rev domain)
  float2 yv[8];
#pragma unroll
  for (int j = 0; j < 8; ++j) {
    int p = tid + (j << 7);
    int f = __brev(p) >> 22;
    int fm = (1024 - f) & 1023;
    int pm = __brev(fm) >> 22;
    float2 A0 = z0[ZPAD(p)], B0 = z0[ZPAD(pm)];
    float2 A1 = z1[ZPAD(p)], B1 = z1[ZPAD(pm)];
    // Q = (A + conj(B))/2 ; K = -i*(A - conj(B))/2 ; P = Q*conj(K)
    float2 Q0 = make_float2(0.5f * (A0.x + B0.x), 0.5f * (A0.y - B0.y));
    float2 iK0 = make_float2(0.5f * (A0.x - B0.x), 0.5f * (A0.y + B0.y));
    float2 K0 = make_float2(iK0.y, -iK0.x);
    float2 P0 = make_float2(Q0.x * K0.x + Q0.y * K0.y,
                            Q0.y * K0.x - Q0.x * K0.y);
    float2 Q1 = make_float2(0.5f * (A1.x + B1.x), 0.5f * (A1.y - B1.y));
    float2 iK1 = make_float2(0.5f * (A1.x - B1.x), 0.5f * (A1.y + B1.y));
    float2 K1 = make_float2(iK1.y, -iK1.x);
    float2 P1 = make_float2(Q1.x * K1.x + Q1.y * K1.y,
                            Q1.y * K1.x - Q1.x * K1.y);
    yv[j] = make_float2(P0.x - P1.y, P0.y + P1.x);
  }
  __syncthreads();
#pragma unroll
  for (int j = 0; j < 8; ++j) {
    int p = tid + (j << 7);
    z0[ZPAD(p)] = yv[j];
  }
  __syncthreads();

  // inverse DIT: bit-reversed in -> natural out
  for (int s = 0; s < 10; ++s) {
    const int hh = 1 << s;
#pragma unroll
    for (int jj = 0; jj < 4; ++jj) {
      const int bb = tid + (jj << 7);
      const int pos = bb & (hh - 1);
      const int idx0 = ((bb >> s) << (s + 1)) | pos;
      const int i0 = ZPAD(idx0), i1 = ZPAD(idx0 + hh);
      const float2 wc = tw[pos << (9 - s)];
      float2 u = z0[i0], v = z0[i1];
      float2 t2 = make_float2(v.x * wc.x + v.y * wc.y,   // v * conj(wc)
                              v.y * wc.x - v.x * wc.y);
      z0[i0] = make_float2(u.x + t2.x, u.y + t2.y);
      z0[i1] = make_float2(u.x - t2.x, u.y - t2.y);
    }
    __syncthreads();
  }

  const float inv = 1.0f / 1024.0f;
#pragma unroll
  for (int j = 0; j < 8; ++j) {
    int t = tid + (j << 7);
    float2 y = z0[ZPAD(t)];
    float vsum = (y.x * y.x + y.y * y.y) * inv * inv;  // c0^2 + c1^2
    atomicAdd(&amp2[(size_t)bh * LSEQ + t], vsum);
  }
}

// ---------------------------------------------------------------------------
// Kernel B: top-35 per (b,h), both branches. Wave-parallel iterative argmax:
// 4 waves x 256-lag segments (register-resident, shfl_xor butterflies),
// then wave 0 merges the 140 candidates. u64 keys = valbits<<32 | (1023-l)
// reproduce lax.top_k tie-breaking; only the selected SET matters downstream.
// ---------------------------------------------------------------------------
__global__ __launch_bounds__(256) void topk_kernel(
    const float* __restrict__ amp2, const float* __restrict__ tfq,
    int* __restrict__ sel_t, int* __restrict__ sel_tf) {
  __shared__ u64 keys[2 * LSEQ];
  __shared__ u64 cand[2][4 * NTOP];
  const int tid = threadIdx.x;
  const int bh = blockIdx.x;
  const int b = bh >> 3, h = bh & 7;
  const size_t base = (size_t)b * (LSEQ * NH * NE) + (size_t)h * NE;

#pragma unroll
  for (int j = 0; j < 4; ++j) {
    int l = tid + (j << 8);
    float a = amp2[(size_t)bh * LSEQ + l];
    keys[l] = ((u64)__float_as_uint(a) << 32) | (unsigned)(LSEQ - 1 - l);
  }
#pragma unroll
  for (int j = 0; j < 4; ++j) {
    int l = tid + (j << 8);
    const float* row = tfq + base + (size_t)l * (NH * NE);
    float s = 0.f;
#pragma unroll
    for (int e = 0; e < NE; e += 4) {
      float4 v = *(const float4*)(row + e);
      s += v.x * v.x + v.y * v.y + v.z * v.z + v.w * v.w;
    }
    keys[LSEQ + l] = ((u64)__float_as_uint(s) << 32) | (unsigned)(LSEQ - 1 - l);
  }
  __syncthreads();

  const int wid = tid >> 6, lane = tid & 63;
  for (int arr = 0; arr < 2; ++arr) {
    const int kb = arr * LSEQ + (wid << 8);
    u64 k0 = keys[kb + lane];
    u64 k1 = keys[kb + 64 + lane];
    u64 k2 = keys[kb + 128 + lane];
    u64 k3 = keys[kb + 192 + lane];
    for (int it = 0; it < NTOP; ++it) {
      u64 m01 = k0 > k1 ? k0 : k1;
      u64 m23 = k2 > k3 ? k2 : k3;
      u64 m = m01 > m23 ? m01 : m23;
#pragma unroll
      for (int off = 32; off > 0; off >>= 1) {
        u64 o = __shfl_xor(m, off);
        m = o > m ? o : m;
      }
      if (k0 == m) k0 = 0;
      else if (k1 == m) k1 = 0;
      else if (k2 == m) k2 = 0;
      else if (k3 == m) k3 = 0;
      if (lane == 0) cand[arr][wid * NTOP + it] = m;
    }
  }
  __syncthreads();

  if (tid < 64) {  // wave 0 merges
    for (int arr = 0; arr < 2; ++arr) {
      u64 c0 = (tid < 4 * NTOP) ? cand[arr][tid] : 0;
      u64 c1 = (tid + 64 < 4 * NTOP) ? cand[arr][tid + 64] : 0;
      u64 c2 = (tid + 128 < 4 * NTOP) ? cand[arr][tid + 128] : 0;
      int* sel = (arr == 0 ? sel_t : sel_tf) + bh * NTOP;
      for (int it = 0; it < NTOP; ++it) {
        u64 m01 = c0 > c1 ? c0 : c1;
        u64 m = m01 > c2 ? m01 : c2;
#pragma unroll
        for (int off = 32; off > 0; off >>= 1) {
          u64 o = __shfl_xor(m, off);
          m = o > m ? o : m;
        }
        if (c0 == m) c0 = 0;
        else if (c1 == m) c1 = 0;
        else if (c2 == m) c2 = 0;
        if (tid == 0) sel[it] = (LSEQ - 1) - (int)(m & 0xffffffffULL);
      }
    }
  }
}

// ---------------------------------------------------------------------------
// Kernel C: scores + per-key softmax (over the 35 selected rows) + mix + PV.
// (unchanged from the passing version)
// ---------------------------------------------------------------------------
__global__ __launch_bounds__(128) void attn_out_kernel(
    const float* __restrict__ qm, const float* __restrict__ tfq,
    const float* __restrict__ km, const float* __restrict__ vm,
    const float* __restrict__ mixw,
    const int* __restrict__ sel_t, const int* __restrict__ sel_tf,
    float* __restrict__ out) {
  const int tid = threadIdx.x;
  const int kc = blockIdx.x & 7;
  const int bh = blockIdx.x >> 3;
  const int b = bh >> 3, h = bh & 7;
  const size_t base = (size_t)b * LSEQ * NH * NE + (size_t)h * NE;

  __shared__ float qs_t[NTOP * NE];
  __shared__ float qs_f[NTOP * NE];
  __shared__ float vs_t[NTOP * NE];
  __shared__ float vs_f[NTOP * NE];

  for (int i = tid; i < NTOP * NE; i += 128) {
    int n = i >> 6, e = i & 63;
    int lt = sel_t[bh * NTOP + n];
    int lf = sel_tf[bh * NTOP + n];
    qs_t[i] = qm[base + (size_t)lt * (NH * NE) + e];
    qs_f[i] = tfq[base + (size_t)lf * (NH * NE) + e];
    vs_t[i] = vm[base + (size_t)lt * (NH * NE) + e];
    vs_f[i] = vm[base + (size_t)lf * (NH * NE) + e];
  }
  __syncthreads();

  const int kpos = (kc << 7) + tid;
  const float* krow = km + base + (size_t)kpos * (NH * NE);
  const float* frow = tfq + base + (size_t)kpos * (NH * NE);

  float st[NTOP], sf[NTOP];
#pragma unroll
  for (int n = 0; n < NTOP; ++n) { st[n] = 0.f; sf[n] = 0.f; }

  for (int e0 = 0; e0 < NE; e0 += 4) {
    float4 kv = *(const float4*)(krow + e0);
    float4 fv = *(const float4*)(frow + e0);
#pragma unroll
    for (int n = 0; n < NTOP; ++n) {
      float4 qt = *(const float4*)(&qs_t[(n << 6) + e0]);
      st[n] = fmaf(qt.x, kv.x, st[n]);
      st[n] = fmaf(qt.y, kv.y, st[n]);
      st[n] = fmaf(qt.z, kv.z, st[n]);
      st[n] = fmaf(qt.w, kv.w, st[n]);
      float4 qf = *(const float4*)(&qs_f[(n << 6) + e0]);
      sf[n] = fmaf(qf.x, fv.x, sf[n]);
      sf[n] = fmaf(qf.y, fv.y, sf[n]);
      sf[n] = fmaf(qf.z, fv.z, sf[n]);
      sf[n] = fmaf(qf.w, fv.w, sf[n]);
    }
  }

  float mt = -1e30f, mf = -1e30f;
#pragma unroll
  for (int n = 0; n < NTOP; ++n) {
    st[n] *= QKSCALE;
    sf[n] *= QKSCALE;
    mt = fmaxf(mt, st[n]);
    mf = fmaxf(mf, sf[n]);
  }
  float sumt = 0.f, sumf = 0.f;
#pragma unroll
  for (int n = 0; n < NTOP; ++n) {
    st[n] = __expf(st[n] - mt); sumt += st[n];
    sf[n] = __expf(sf[n] - mf); sumf += sf[n];
  }
  const float m0 = mixw[((size_t)h * LSEQ + kpos) * 2 + 0];
  const float m1 = mixw[((size_t)h * LSEQ + kpos) * 2 + 1];
  const float e0w = __expf(m0), e1w = __expf(m1);
  const float inv = 1.f / (e0w + e1w);
  const float ct = e0w * inv / sumt;
  const float cf = e1w * inv / sumf;
#pragma unroll
  for (int n = 0; n < NTOP; ++n) { st[n] *= ct; sf[n] *= cf; }

  float* orow = out + (size_t)bh * NE * LSEQ + kpos;
  for (int d0 = 0; d0 < NE; d0 += 4) {
    float a0 = 0.f, a1 = 0.f, a2 = 0.f, a3 = 0.f;
#pragma unroll
    for (int n = 0; n < NTOP; ++n) {
      float4 vt = *(const float4*)(&vs_t[(n << 6) + d0]);
      float4 vf = *(const float4*)(&vs_f[(n << 6) + d0]);
      a0 = fmaf(st[n], vt.x, a0); a0 = fmaf(sf[n], vf.x, a0);
      a1 = fmaf(st[n], vt.y, a1); a1 = fmaf(sf[n], vf.y, a1);
      a2 = fmaf(st[n], vt.z, a2); a2 = fmaf(sf[n], vf.z, a2);
      a3 = fmaf(st[n], vt.w, a3); a3 = fmaf(sf[n], vf.w, a3);
    }
    orow[(size_t)(d0 + 0) * LSEQ] = a0;
    orow[(size_t)(d0 + 1) * LSEQ] = a1;
    orow[(size_t)(d0 + 2) * LSEQ] = a2;
    orow[(size_t)(d0 + 3) * LSEQ] = a3;
  }
}

// ---------------------------------------------------------------------------
extern "C" void kernel_launch(void* const* d_in, const int* in_sizes, int n_in,
                              void* d_out, int out_size, void* d_ws, size_t ws_size,
                              hipStream_t stream) {
  const float* tfq  = (const float*)d_in[0];
  const float* qm   = (const float*)d_in[1];
  const float* km   = (const float*)d_in[2];
  const float* vm   = (const float*)d_in[3];
  const float* mixw = (const float*)d_in[6];
  // d_in[4], d_in[5] (weights1_*), d_in[7] (mask), d_in[8] (mode_index):
  // dead code w.r.t. the returned output — skipped.

  float* amp2  = (float*)d_ws;                                   // 32*1024 f32
  int*   sel_t = (int*)((char*)d_ws + sizeof(float) * 32 * LSEQ);
  int*   sel_tf = sel_t + 32 * NTOP;
  float* out = (float*)d_out;

  zero_kernel<<<dim3(128), dim3(256), 0, stream>>>(amp2, 32 * LSEQ);
  corr_fft_kernel<<<dim3(1024), dim3(128), 0, stream>>>(qm, km, amp2);
  topk_kernel<<<dim3(32), dim3(256), 0, stream>>>(amp2, tfq, sel_t, sel_tf);
  attn_out_kernel<<<dim3(256), dim3(128), 0, stream>>>(qm, tfq, km, vm, mixw,
                                                       sel_t, sel_tf, out);
}

// Round 3
// 115.517 us; speedup vs baseline: 1.7002x; 1.2736x over previous
//
#include <hip/hip_runtime.h>

#define LSEQ 1024
#define NH 8
#define NE 64
#define NTOP 35
#define QKSCALE 0.04419417382415922f   // 1/sqrt(512)

typedef unsigned long long u64;

#define ZPAD(i) ((i) + ((i) >> 5))     // pad 1 float2 per 32 -> 1056 slots

// ---------------------------------------------------------------------------
// Zero amp2 (graph-capture-safe init; harness does not re-poison between runs)
// ---------------------------------------------------------------------------
__global__ void zero_kernel(float* __restrict__ p, int n) {
  int i = blockIdx.x * 256 + threadIdx.x;
  if (i < n) p[i] = 0.f;
}

// ---------------------------------------------------------------------------
// Kernel A (FFT): circular cross-correlation amplitude^2 via packed FFTs.
// One block per (bh, channel-pair): z_e = q_e + i*k_e (2 fwd FFTs),
// P_e = Q_e * conj(K_e) extracted via Hermitian partners in bit-rev domain,
// Y = P0 + i*P1 (1 inv FFT) -> y_t = c0_t + i*c1_t -> amp2 += |y_t|^2.
// ---------------------------------------------------------------------------
__global__ __launch_bounds__(128) void corr_fft_kernel(
    const float* __restrict__ qm, const float* __restrict__ km,
    float* __restrict__ amp2) {
  const int tid  = threadIdx.x;
  const int bh   = blockIdx.x & 31;
  const int pair = blockIdx.x >> 5;
  const int b = bh >> 3, h = bh & 7;
  const int e0 = pair << 1;
  const size_t base = (size_t)b * (LSEQ * NH * NE) + (size_t)h * NE + e0;

  __shared__ float2 z0[1056];
  __shared__ float2 z1[1056];
  __shared__ float2 tw[512];   // exp(-2*pi*i*j/1024)

  for (int j = tid; j < 512; j += 128) {
    float s, c;
    sincosf(6.283185307179586f * (float)j * (1.0f / 1024.0f), &s, &c);
    tw[j] = make_float2(c, -s);
  }
#pragma unroll
  for (int j = 0; j < 8; ++j) {
    int t = tid + (j << 7);
    float2 qv = *(const float2*)(qm + base + (size_t)t * (NH * NE));
    float2 kv = *(const float2*)(km + base + (size_t)t * (NH * NE));
    z0[ZPAD(t)] = make_float2(qv.x, kv.x);
    z1[ZPAD(t)] = make_float2(qv.y, kv.y);
  }
  __syncthreads();

  // forward DIF: natural in -> bit-reversed out, for z0 and z1
  for (int s = 0; s < 10; ++s) {
    const int hh = 512 >> s;
#pragma unroll
    for (int jj = 0; jj < 4; ++jj) {
      const int bb = tid + (jj << 7);
      const int pos = bb & (hh - 1);
      const int idx0 = ((bb >> (9 - s)) << (10 - s)) | pos;
      const int i0 = ZPAD(idx0), i1 = ZPAD(idx0 + hh);
      const float2 w = tw[pos << s];
      float2 u, v, d;
      u = z0[i0]; v = z0[i1];
      z0[i0] = make_float2(u.x + v.x, u.y + v.y);
      d = make_float2(u.x - v.x, u.y - v.y);
      z0[i1] = make_float2(d.x * w.x - d.y * w.y, d.x * w.y + d.y * w.x);
      u = z1[i0]; v = z1[i1];
      z1[i0] = make_float2(u.x + v.x, u.y + v.y);
      d = make_float2(u.x - v.x, u.y - v.y);
      z1[i1] = make_float2(d.x * w.x - d.y * w.y, d.x * w.y + d.y * w.x);
    }
    __syncthreads();
  }

  // pointwise: P = Q*conj(K) per channel, pack Y = P0 + i*P1 (bit-rev domain)
  float2 yv[8];
#pragma unroll
  for (int j = 0; j < 8; ++j) {
    int p = tid + (j << 7);
    int f = __brev(p) >> 22;
    int fm = (1024 - f) & 1023;
    int pm = __brev(fm) >> 22;
    float2 A0 = z0[ZPAD(p)], B0 = z0[ZPAD(pm)];
    float2 A1 = z1[ZPAD(p)], B1 = z1[ZPAD(pm)];
    // Q = (A + conj(B))/2 ; K = -i*(A - conj(B))/2 ; P = Q*conj(K)
    float2 Q0 = make_float2(0.5f * (A0.x + B0.x), 0.5f * (A0.y - B0.y));
    float2 iK0 = make_float2(0.5f * (A0.x - B0.x), 0.5f * (A0.y + B0.y));
    float2 K0 = make_float2(iK0.y, -iK0.x);
    float2 P0 = make_float2(Q0.x * K0.x + Q0.y * K0.y,
                            Q0.y * K0.x - Q0.x * K0.y);
    float2 Q1 = make_float2(0.5f * (A1.x + B1.x), 0.5f * (A1.y - B1.y));
    float2 iK1 = make_float2(0.5f * (A1.x - B1.x), 0.5f * (A1.y + B1.y));
    float2 K1 = make_float2(iK1.y, -iK1.x);
    float2 P1 = make_float2(Q1.x * K1.x + Q1.y * K1.y,
                            Q1.y * K1.x - Q1.x * K1.y);
    yv[j] = make_float2(P0.x - P1.y, P0.y + P1.x);
  }
  __syncthreads();
#pragma unroll
  for (int j = 0; j < 8; ++j) {
    int p = tid + (j << 7);
    z0[ZPAD(p)] = yv[j];
  }
  __syncthreads();

  // inverse DIT: bit-reversed in -> natural out
  for (int s = 0; s < 10; ++s) {
    const int hh = 1 << s;
#pragma unroll
    for (int jj = 0; jj < 4; ++jj) {
      const int bb = tid + (jj << 7);
      const int pos = bb & (hh - 1);
      const int idx0 = ((bb >> s) << (s + 1)) | pos;
      const int i0 = ZPAD(idx0), i1 = ZPAD(idx0 + hh);
      const float2 wc = tw[pos << (9 - s)];
      float2 u = z0[i0], v = z0[i1];
      float2 t2 = make_float2(v.x * wc.x + v.y * wc.y,   // v * conj(wc)
                              v.y * wc.x - v.x * wc.y);
      z0[i0] = make_float2(u.x + t2.x, u.y + t2.y);
      z0[i1] = make_float2(u.x - t2.x, u.y - t2.y);
    }
    __syncthreads();
  }

  const float inv = 1.0f / 1024.0f;
#pragma unroll
  for (int j = 0; j < 8; ++j) {
    int t = tid + (j << 7);
    float2 y = z0[ZPAD(t)];
    float vsum = (y.x * y.x + y.y * y.y) * inv * inv;  // c0^2 + c1^2
    atomicAdd(&amp2[(size_t)bh * LSEQ + t], vsum);
  }
}

// ---------------------------------------------------------------------------
// Kernel N: tf_queries row-norm^2, fully parallel + coalesced.
// Row id rid = ((b*1024 + l)*8 + h); rows are contiguous 64-float chunks.
// 16 lanes per row (one float4 each), shfl_xor reduce within the 16-group.
// grid = 2048 blocks x 256 threads -> 16 rows/block.
// ---------------------------------------------------------------------------
__global__ __launch_bounds__(256) void norm_kernel(
    const float* __restrict__ tfq, float* __restrict__ norms) {
  const int tid = threadIdx.x;
  const int rid = blockIdx.x * 16 + (tid >> 4);   // 16 rows per block
  const int le = tid & 15;
  float4 v = *(const float4*)(tfq + (size_t)rid * NE + (le << 2));
  float s = v.x * v.x + v.y * v.y + v.z * v.z + v.w * v.w;
#pragma unroll
  for (int off = 8; off > 0; off >>= 1) s += __shfl_xor(s, off, 16);
  if (le == 0) {
    int b = rid >> 13, l = (rid >> 3) & 1023, h = rid & 7;
    norms[(size_t)(b * 8 + h) * LSEQ + l] = s;
  }
}

// ---------------------------------------------------------------------------
// Kernel B: top-35 selection. One block per (bh, branch) = 64 blocks.
// Scores pre-computed (amp2 / norms): 4KB read per block. Register-resident
// wave argmax (35 rounds of shfl_xor u64 butterflies), wave 0 merges 140.
// u64 keys = valbits<<32 | (1023-l) reproduce lax.top_k tie-breaking.
// ---------------------------------------------------------------------------
__global__ __launch_bounds__(256) void topk_kernel(
    const float* __restrict__ amp2, const float* __restrict__ norms,
    int* __restrict__ sel_t, int* __restrict__ sel_tf) {
  __shared__ u64 cand[4 * NTOP];
  const int tid = threadIdx.x;
  const int bh = blockIdx.x & 31;
  const int arr = blockIdx.x >> 5;
  const float* sc = (arr == 0 ? amp2 : norms) + (size_t)bh * LSEQ;
  int* sel = (arr == 0 ? sel_t : sel_tf) + bh * NTOP;

  const int wid = tid >> 6, lane = tid & 63;
  const int kb = wid << 8;
  u64 k0, k1, k2, k3;
  {
    int l;
    l = kb + lane;
    k0 = ((u64)__float_as_uint(sc[l]) << 32) | (unsigned)(LSEQ - 1 - l);
    l = kb + 64 + lane;
    k1 = ((u64)__float_as_uint(sc[l]) << 32) | (unsigned)(LSEQ - 1 - l);
    l = kb + 128 + lane;
    k2 = ((u64)__float_as_uint(sc[l]) << 32) | (unsigned)(LSEQ - 1 - l);
    l = kb + 192 + lane;
    k3 = ((u64)__float_as_uint(sc[l]) << 32) | (unsigned)(LSEQ - 1 - l);
  }
  for (int it = 0; it < NTOP; ++it) {
    u64 m01 = k0 > k1 ? k0 : k1;
    u64 m23 = k2 > k3 ? k2 : k3;
    u64 m = m01 > m23 ? m01 : m23;
#pragma unroll
    for (int off = 32; off > 0; off >>= 1) {
      u64 o = __shfl_xor(m, off);
      m = o > m ? o : m;
    }
    if (k0 == m) k0 = 0;
    else if (k1 == m) k1 = 0;
    else if (k2 == m) k2 = 0;
    else if (k3 == m) k3 = 0;
    if (lane == 0) cand[wid * NTOP + it] = m;
  }
  __syncthreads();

  if (tid < 64) {  // wave 0 merges 140 candidates
    u64 c0 = (tid < 4 * NTOP) ? cand[tid] : 0;
    u64 c1 = (tid + 64 < 4 * NTOP) ? cand[tid + 64] : 0;
    u64 c2 = (tid + 128 < 4 * NTOP) ? cand[tid + 128] : 0;
    for (int it = 0; it < NTOP; ++it) {
      u64 m01 = c0 > c1 ? c0 : c1;
      u64 m = m01 > c2 ? m01 : c2;
#pragma unroll
      for (int off = 32; off > 0; off >>= 1) {
        u64 o = __shfl_xor(m, off);
        m = o > m ? o : m;
      }
      if (c0 == m) c0 = 0;
      else if (c1 == m) c1 = 0;
      else if (c2 == m) c2 = 0;
      if (tid == 0) sel[it] = (LSEQ - 1) - (int)(m & 0xffffffffULL);
    }
  }
}

// ---------------------------------------------------------------------------
// Kernel C: scores + per-key softmax (over the 35 selected rows) + mix + PV.
// ---------------------------------------------------------------------------
__global__ __launch_bounds__(128) void attn_out_kernel(
    const float* __restrict__ qm, const float* __restrict__ tfq,
    const float* __restrict__ km, const float* __restrict__ vm,
    const float* __restrict__ mixw,
    const int* __restrict__ sel_t, const int* __restrict__ sel_tf,
    float* __restrict__ out) {
  const int tid = threadIdx.x;
  const int kc = blockIdx.x & 7;
  const int bh = blockIdx.x >> 3;
  const int b = bh >> 3, h = bh & 7;
  const size_t base = (size_t)b * LSEQ * NH * NE + (size_t)h * NE;

  __shared__ float qs_t[NTOP * NE];
  __shared__ float qs_f[NTOP * NE];
  __shared__ float vs_t[NTOP * NE];
  __shared__ float vs_f[NTOP * NE];

  for (int i = tid; i < NTOP * NE; i += 128) {
    int n = i >> 6, e = i & 63;
    int lt = sel_t[bh * NTOP + n];
    int lf = sel_tf[bh * NTOP + n];
    qs_t[i] = qm[base + (size_t)lt * (NH * NE) + e];
    qs_f[i] = tfq[base + (size_t)lf * (NH * NE) + e];
    vs_t[i] = vm[base + (size_t)lt * (NH * NE) + e];
    vs_f[i] = vm[base + (size_t)lf * (NH * NE) + e];
  }
  __syncthreads();

  const int kpos = (kc << 7) + tid;
  const float* krow = km + base + (size_t)kpos * (NH * NE);
  const float* frow = tfq + base + (size_t)kpos * (NH * NE);

  float st[NTOP], sf[NTOP];
#pragma unroll
  for (int n = 0; n < NTOP; ++n) { st[n] = 0.f; sf[n] = 0.f; }

  for (int e0 = 0; e0 < NE; e0 += 4) {
    float4 kv = *(const float4*)(krow + e0);
    float4 fv = *(const float4*)(frow + e0);
#pragma unroll
    for (int n = 0; n < NTOP; ++n) {
      float4 qt = *(const float4*)(&qs_t[(n << 6) + e0]);
      st[n] = fmaf(qt.x, kv.x, st[n]);
      st[n] = fmaf(qt.y, kv.y, st[n]);
      st[n] = fmaf(qt.z, kv.z, st[n]);
      st[n] = fmaf(qt.w, kv.w, st[n]);
      float4 qf = *(const float4*)(&qs_f[(n << 6) + e0]);
      sf[n] = fmaf(qf.x, fv.x, sf[n]);
      sf[n] = fmaf(qf.y, fv.y, sf[n]);
      sf[n] = fmaf(qf.z, fv.z, sf[n]);
      sf[n] = fmaf(qf.w, fv.w, sf[n]);
    }
  }

  float mt = -1e30f, mf = -1e30f;
#pragma unroll
  for (int n = 0; n < NTOP; ++n) {
    st[n] *= QKSCALE;
    sf[n] *= QKSCALE;
    mt = fmaxf(mt, st[n]);
    mf = fmaxf(mf, sf[n]);
  }
  float sumt = 0.f, sumf = 0.f;
#pragma unroll
  for (int n = 0; n < NTOP; ++n) {
    st[n] = __expf(st[n] - mt); sumt += st[n];
    sf[n] = __expf(sf[n] - mf); sumf += sf[n];
  }
  const float m0 = mixw[((size_t)h * LSEQ + kpos) * 2 + 0];
  const float m1 = mixw[((size_t)h * LSEQ + kpos) * 2 + 1];
  const float e0w = __expf(m0), e1w = __expf(m1);
  const float inv = 1.f / (e0w + e1w);
  const float ct = e0w * inv / sumt;
  const float cf = e1w * inv / sumf;
#pragma unroll
  for (int n = 0; n < NTOP; ++n) { st[n] *= ct; sf[n] *= cf; }

  float* orow = out + (size_t)bh * NE * LSEQ + kpos;
  for (int d0 = 0; d0 < NE; d0 += 4) {
    float a0 = 0.f, a1 = 0.f, a2 = 0.f, a3 = 0.f;
#pragma unroll
    for (int n = 0; n < NTOP; ++n) {
      float4 vt = *(const float4*)(&vs_t[(n << 6) + d0]);
      float4 vf = *(const float4*)(&vs_f[(n << 6) + d0]);
      a0 = fmaf(st[n], vt.x, a0); a0 = fmaf(sf[n], vf.x, a0);
      a1 = fmaf(st[n], vt.y, a1); a1 = fmaf(sf[n], vf.y, a1);
      a2 = fmaf(st[n], vt.z, a2); a2 = fmaf(sf[n], vf.z, a2);
      a3 = fmaf(st[n], vt.w, a3); a3 = fmaf(sf[n], vf.w, a3);
    }
    orow[(size_t)(d0 + 0) * LSEQ] = a0;
    orow[(size_t)(d0 + 1) * LSEQ] = a1;
    orow[(size_t)(d0 + 2) * LSEQ] = a2;
    orow[(size_t)(d0 + 3) * LSEQ] = a3;
  }
}

// ---------------------------------------------------------------------------
extern "C" void kernel_launch(void* const* d_in, const int* in_sizes, int n_in,
                              void* d_out, int out_size, void* d_ws, size_t ws_size,
                              hipStream_t stream) {
  const float* tfq  = (const float*)d_in[0];
  const float* qm   = (const float*)d_in[1];
  const float* km   = (const float*)d_in[2];
  const float* vm   = (const float*)d_in[3];
  const float* mixw = (const float*)d_in[6];
  // d_in[4], d_in[5] (weights1_*), d_in[7] (mask), d_in[8] (mode_index):
  // dead code w.r.t. the returned output — skipped.

  float* amp2   = (float*)d_ws;                                  // 32*1024 f32
  float* norms  = amp2 + 32 * LSEQ;                              // 32*1024 f32
  int*   sel_t  = (int*)(norms + 32 * LSEQ);
  int*   sel_tf = sel_t + 32 * NTOP;
  float* out = (float*)d_out;

  zero_kernel<<<dim3(128), dim3(256), 0, stream>>>(amp2, 32 * LSEQ);
  norm_kernel<<<dim3(2048), dim3(256), 0, stream>>>(tfq, norms);
  corr_fft_kernel<<<dim3(1024), dim3(128), 0, stream>>>(qm, km, amp2);
  topk_kernel<<<dim3(64), dim3(256), 0, stream>>>(amp2, norms, sel_t, sel_tf);
  attn_out_kernel<<<dim3(256), dim3(128), 0, stream>>>(qm, tfq, km, vm, mixw,
                                                       sel_t, sel_tf, out);
}

// Round 4
// 88.649 us; speedup vs baseline: 2.2156x; 1.3031x over previous
//
#include <hip/hip_runtime.h>

#define LSEQ 1024
#define NH 8
#define NE 64
#define NTOP 35
#define QKSCALE 0.04419417382415922f   // 1/sqrt(512)

typedef unsigned long long u64;

#define ZPAD(i) ((i) + ((i) >> 5))     // pad 1 float2 per 32 -> 1056 slots

#define FMA4(d, v, sc) \
  (d).x = fmaf((v).x, (sc), (d).x); (d).y = fmaf((v).y, (sc), (d).y); \
  (d).z = fmaf((v).z, (sc), (d).z); (d).w = fmaf((v).w, (sc), (d).w);

// ---------------------------------------------------------------------------
__global__ void zero_kernel(float* __restrict__ p, int n) {
  int i = blockIdx.x * 256 + threadIdx.x;
  if (i < n) p[i] = 0.f;
}

// Twiddle table exp(-2*pi*i*j/1024), j in [0,512): computed once per call.
__global__ void tw_kernel(float2* __restrict__ twg) {
  int j = blockIdx.x * 256 + threadIdx.x;
  if (j < 512) {
    float s, c;
    sincosf(6.283185307179586f * (float)j * (1.0f / 1024.0f), &s, &c);
    twg[j] = make_float2(c, -s);
  }
}

// ---------------------------------------------------------------------------
// Kernel A (FFT): circular cross-correlation amplitude^2 via packed FFTs.
// ---------------------------------------------------------------------------
__global__ __launch_bounds__(128) void corr_fft_kernel(
    const float* __restrict__ qm, const float* __restrict__ km,
    const float2* __restrict__ twg, float* __restrict__ amp2) {
  const int tid  = threadIdx.x;
  const int bh   = blockIdx.x & 31;
  const int pair = blockIdx.x >> 5;
  const int b = bh >> 3, h = bh & 7;
  const int e0 = pair << 1;
  const size_t base = (size_t)b * (LSEQ * NH * NE) + (size_t)h * NE + e0;

  __shared__ float2 z0[1056];
  __shared__ float2 z1[1056];
  __shared__ float2 tw[512];

#pragma unroll
  for (int j = 0; j < 4; ++j) tw[tid + (j << 7)] = twg[tid + (j << 7)];
#pragma unroll
  for (int j = 0; j < 8; ++j) {
    int t = tid + (j << 7);
    float2 qv = *(const float2*)(qm + base + (size_t)t * (NH * NE));
    float2 kv = *(const float2*)(km + base + (size_t)t * (NH * NE));
    z0[ZPAD(t)] = make_float2(qv.x, kv.x);
    z1[ZPAD(t)] = make_float2(qv.y, kv.y);
  }
  __syncthreads();

  // forward DIF: natural in -> bit-reversed out
  for (int s = 0; s < 10; ++s) {
    const int hh = 512 >> s;
#pragma unroll
    for (int jj = 0; jj < 4; ++jj) {
      const int bb = tid + (jj << 7);
      const int pos = bb & (hh - 1);
      const int idx0 = ((bb >> (9 - s)) << (10 - s)) | pos;
      const int i0 = ZPAD(idx0), i1 = ZPAD(idx0 + hh);
      const float2 w = tw[pos << s];
      float2 u, v, d;
      u = z0[i0]; v = z0[i1];
      z0[i0] = make_float2(u.x + v.x, u.y + v.y);
      d = make_float2(u.x - v.x, u.y - v.y);
      z0[i1] = make_float2(d.x * w.x - d.y * w.y, d.x * w.y + d.y * w.x);
      u = z1[i0]; v = z1[i1];
      z1[i0] = make_float2(u.x + v.x, u.y + v.y);
      d = make_float2(u.x - v.x, u.y - v.y);
      z1[i1] = make_float2(d.x * w.x - d.y * w.y, d.x * w.y + d.y * w.x);
    }
    __syncthreads();
  }

  // pointwise P = Q*conj(K); pack Y = P0 + i*P1 (bit-rev domain)
  float2 yv[8];
#pragma unroll
  for (int j = 0; j < 8; ++j) {
    int p = tid + (j << 7);
    int f = __brev(p) >> 22;
    int fm = (1024 - f) & 1023;
    int pm = __brev(fm) >> 22;
    float2 A0 = z0[ZPAD(p)], B0 = z0[ZPAD(pm)];
    float2 A1 = z1[ZPAD(p)], B1 = z1[ZPAD(pm)];
    float2 Q0 = make_float2(0.5f * (A0.x + B0.x), 0.5f * (A0.y - B0.y));
    float2 iK0 = make_float2(0.5f * (A0.x - B0.x), 0.5f * (A0.y + B0.y));
    float2 K0 = make_float2(iK0.y, -iK0.x);
    float2 P0 = make_float2(Q0.x * K0.x + Q0.y * K0.y,
                            Q0.y * K0.x - Q0.x * K0.y);
    float2 Q1 = make_float2(0.5f * (A1.x + B1.x), 0.5f * (A1.y - B1.y));
    float2 iK1 = make_float2(0.5f * (A1.x - B1.x), 0.5f * (A1.y + B1.y));
    float2 K1 = make_float2(iK1.y, -iK1.x);
    float2 P1 = make_float2(Q1.x * K1.x + Q1.y * K1.y,
                            Q1.y * K1.x - Q1.x * K1.y);
    yv[j] = make_float2(P0.x - P1.y, P0.y + P1.x);
  }
  __syncthreads();
#pragma unroll
  for (int j = 0; j < 8; ++j) z0[ZPAD(tid + (j << 7))] = yv[j];
  __syncthreads();

  // inverse DIT: bit-reversed in -> natural out
  for (int s = 0; s < 10; ++s) {
    const int hh = 1 << s;
#pragma unroll
    for (int jj = 0; jj < 4; ++jj) {
      const int bb = tid + (jj << 7);
      const int pos = bb & (hh - 1);
      const int idx0 = ((bb >> s) << (s + 1)) | pos;
      const int i0 = ZPAD(idx0), i1 = ZPAD(idx0 + hh);
      const float2 wc = tw[pos << (9 - s)];
      float2 u = z0[i0], v = z0[i1];
      float2 t2 = make_float2(v.x * wc.x + v.y * wc.y,
                              v.y * wc.x - v.x * wc.y);
      z0[i0] = make_float2(u.x + t2.x, u.y + t2.y);
      z0[i1] = make_float2(u.x - t2.x, u.y - t2.y);
    }
    __syncthreads();
  }

  const float inv = 1.0f / 1024.0f;
#pragma unroll
  for (int j = 0; j < 8; ++j) {
    int t = tid + (j << 7);
    float2 y = z0[ZPAD(t)];
    atomicAdd(&amp2[(size_t)bh * LSEQ + t], (y.x * y.x + y.y * y.y) * inv * inv);
  }
}

// ---------------------------------------------------------------------------
// Kernel N: tf_queries row-norm^2 (coalesced, saturating grid).
// ---------------------------------------------------------------------------
__global__ __launch_bounds__(256) void norm_kernel(
    const float* __restrict__ tfq, float* __restrict__ norms) {
  const int tid = threadIdx.x;
  const int rid = blockIdx.x * 16 + (tid >> 4);
  const int le = tid & 15;
  float4 v = *(const float4*)(tfq + (size_t)rid * NE + (le << 2));
  float s = v.x * v.x + v.y * v.y + v.z * v.z + v.w * v.w;
#pragma unroll
  for (int off = 8; off > 0; off >>= 1) s += __shfl_xor(s, off, 16);
  if (le == 0) {
    int b = rid >> 13, l = (rid >> 3) & 1023, h = rid & 7;
    norms[(size_t)(b * 8 + h) * LSEQ + l] = s;
  }
}

// ---------------------------------------------------------------------------
// Kernel B: top-35 per (bh, branch). u64 keys reproduce lax.top_k tie-break.
// ---------------------------------------------------------------------------
__global__ __launch_bounds__(256) void topk_kernel(
    const float* __restrict__ amp2, const float* __restrict__ norms,
    int* __restrict__ sel_t, int* __restrict__ sel_tf) {
  __shared__ u64 cand[4 * NTOP];
  const int tid = threadIdx.x;
  const int bh = blockIdx.x & 31;
  const int arr = blockIdx.x >> 5;
  const float* sc = (arr == 0 ? amp2 : norms) + (size_t)bh * LSEQ;
  int* sel = (arr == 0 ? sel_t : sel_tf) + bh * NTOP;

  const int wid = tid >> 6, lane = tid & 63;
  const int kb = wid << 8;
  u64 k0, k1, k2, k3;
  {
    int l;
    l = kb + lane;
    k0 = ((u64)__float_as_uint(sc[l]) << 32) | (unsigned)(LSEQ - 1 - l);
    l = kb + 64 + lane;
    k1 = ((u64)__float_as_uint(sc[l]) << 32) | (unsigned)(LSEQ - 1 - l);
    l = kb + 128 + lane;
    k2 = ((u64)__float_as_uint(sc[l]) << 32) | (unsigned)(LSEQ - 1 - l);
    l = kb + 192 + lane;
    k3 = ((u64)__float_as_uint(sc[l]) << 32) | (unsigned)(LSEQ - 1 - l);
  }
  for (int it = 0; it < NTOP; ++it) {
    u64 m01 = k0 > k1 ? k0 : k1;
    u64 m23 = k2 > k3 ? k2 : k3;
    u64 m = m01 > m23 ? m01 : m23;
#pragma unroll
    for (int off = 32; off > 0; off >>= 1) {
      u64 o = __shfl_xor(m, off);
      m = o > m ? o : m;
    }
    if (k0 == m) k0 = 0;
    else if (k1 == m) k1 = 0;
    else if (k2 == m) k2 = 0;
    else if (k3 == m) k3 = 0;
    if (lane == 0) cand[wid * NTOP + it] = m;
  }
  __syncthreads();

  if (tid < 64) {
    u64 c0 = (tid < 4 * NTOP) ? cand[tid] : 0;
    u64 c1 = (tid + 64 < 4 * NTOP) ? cand[tid + 64] : 0;
    u64 c2 = (tid + 128 < 4 * NTOP) ? cand[tid + 128] : 0;
    for (int it = 0; it < NTOP; ++it) {
      u64 m01 = c0 > c1 ? c0 : c1;
      u64 m = m01 > c2 ? m01 : c2;
#pragma unroll
      for (int off = 32; off > 0; off >>= 1) {
        u64 o = __shfl_xor(m, off);
        m = o > m ? o : m;
      }
      if (c0 == m) c0 = 0;
      else if (c1 == m) c1 = 0;
      else if (c2 == m) c2 = 0;
      if (tid == 0) sel[it] = (LSEQ - 1) - (int)(m & 0xffffffffULL);
    }
  }
}

// ---------------------------------------------------------------------------
// Kernel C v2: register-tiled two-GEMM attention tail.
// Per block: (bh, 128-key chunk). Phases:
//  1. stage Q[2][40][68] (selected rows, 5-row pad zeroed), V[2][36][68],
//  2. per branch: stage X[e][k] transposed (K rows / tfq rows), score GEMM
//     (thread tile 5n x 4k, 9 b128 LDS reads per 80 FMA) -> S[2][40][132],
//  3. column softmax over the 35 rows + mix-weight scaling (P in-place),
//  4. PV GEMM (thread tile 8d x 4k) -> out[bh][d][k].
// ---------------------------------------------------------------------------
__global__ __launch_bounds__(256) void attn_out_kernel(
    const float* __restrict__ qm, const float* __restrict__ tfq,
    const float* __restrict__ km, const float* __restrict__ vm,
    const float* __restrict__ mixw,
    const int* __restrict__ sel_t, const int* __restrict__ sel_tf,
    float* __restrict__ out) {
  __shared__ float Qs[2 * 40 * 68];   // 21.3 KB
  __shared__ float Xs[64 * 132];      // 33.0 KB
  __shared__ float Ss[2 * 40 * 132];  // 41.3 KB
  __shared__ float Vs[2 * 36 * 68];   // 19.1 KB   (total ~114.6 KB)

  const int tid = threadIdx.x;
  const int kc = blockIdx.x & 7;
  const int bh = blockIdx.x >> 3;
  const int b = bh >> 3, h = bh & 7;
  const int k0 = kc << 7;
  const size_t base = (size_t)b * (LSEQ * NH * NE) + (size_t)h * NE;

  // ---- stage Q (both branches; rows 35..39 zero) and V ----
  for (int i = tid; i < 1280; i += 256) {
    int r = i >> 4, e4 = (i & 15) << 2;
    int br = r / 40, n = r - br * 40;
    float4 v = make_float4(0.f, 0.f, 0.f, 0.f);
    if (n < NTOP) {
      int l = (br ? sel_tf : sel_t)[bh * NTOP + n];
      v = *(const float4*)((br ? tfq : qm) + base + (size_t)l * (NH * NE) + e4);
    }
    *(float4*)&Qs[r * 68 + e4] = v;
  }
  for (int i = tid; i < 1152; i += 256) {
    int r = i >> 4, e4 = (i & 15) << 2;
    int br = r / 36, n = r - br * 36;
    float4 v = make_float4(0.f, 0.f, 0.f, 0.f);
    if (n < NTOP) {
      int l = (br ? sel_tf : sel_t)[bh * NTOP + n];
      v = *(const float4*)(vm + base + (size_t)l * (NH * NE) + e4);
    }
    *(float4*)&Vs[r * 68 + e4] = v;
  }

  const int s = tid >> 5;            // n-strip 0..7 (rows 5s..5s+4)
  const int kq2 = (tid & 31) << 2;   // key quad offset 0..124

  // ---- per-branch: stage X transposed, score GEMM ----
  for (int br = 0; br < 2; ++br) {
    __syncthreads();   // Q/V staged (br=0) / previous GEMM done reading Xs
    const float* xsrc = (br ? tfq : km);
    for (int i = tid; i < 2048; i += 256) {
      int k = i >> 4, e4 = (i & 15) << 2;
      float4 v = *(const float4*)(xsrc + base + (size_t)(k0 + k) * (NH * NE) + e4);
      Xs[(e4 + 0) * 132 + k] = v.x;
      Xs[(e4 + 1) * 132 + k] = v.y;
      Xs[(e4 + 2) * 132 + k] = v.z;
      Xs[(e4 + 3) * 132 + k] = v.w;
    }
    __syncthreads();

    float4 acc[5];
#pragma unroll
    for (int m = 0; m < 5; ++m) acc[m] = make_float4(0.f, 0.f, 0.f, 0.f);
    for (int e0 = 0; e0 < NE; e0 += 4) {
      float4 xv0 = *(const float4*)&Xs[(e0 + 0) * 132 + kq2];
      float4 xv1 = *(const float4*)&Xs[(e0 + 1) * 132 + kq2];
      float4 xv2 = *(const float4*)&Xs[(e0 + 2) * 132 + kq2];
      float4 xv3 = *(const float4*)&Xs[(e0 + 3) * 132 + kq2];
#pragma unroll
      for (int m = 0; m < 5; ++m) {
        float4 qv = *(const float4*)&Qs[(br * 40 + 5 * s + m) * 68 + e0];
        FMA4(acc[m], xv0, qv.x);
        FMA4(acc[m], xv1, qv.y);
        FMA4(acc[m], xv2, qv.z);
        FMA4(acc[m], xv3, qv.w);
      }
    }
#pragma unroll
    for (int m = 0; m < 5; ++m)
      *(float4*)&Ss[(br * 40 + 5 * s + m) * 132 + kq2] = acc[m];
  }
  __syncthreads();

  // ---- per-key softmax over the 35 rows + mix coefficient ----
  {
    const int k = tid & 127, br = tid >> 7;
    float p[NTOP];
    float mx = -1e30f;
#pragma unroll
    for (int n = 0; n < NTOP; ++n) {
      p[n] = Ss[(br * 40 + n) * 132 + k] * QKSCALE;
      mx = fmaxf(mx, p[n]);
    }
    float sum = 0.f;
#pragma unroll
    for (int n = 0; n < NTOP; ++n) { p[n] = __expf(p[n] - mx); sum += p[n]; }
    const float w0 = mixw[(size_t)h * (LSEQ * 2) + (size_t)(k0 + k) * 2 + 0];
    const float w1 = mixw[(size_t)h * (LSEQ * 2) + (size_t)(k0 + k) * 2 + 1];
    const float ew0 = __expf(w0), ew1 = __expf(w1);
    const float c = (br ? ew1 : ew0) / ((ew0 + ew1) * sum);
#pragma unroll
    for (int n = 0; n < NTOP; ++n) Ss[(br * 40 + n) * 132 + k] = p[n] * c;
  }
  __syncthreads();

  // ---- PV GEMM: thread tile 8d x 4k ----
  {
    const int ds8 = (tid >> 5) << 3;   // d base 0..56
    float4 a[2][4];
#pragma unroll
    for (int i = 0; i < 2; ++i)
#pragma unroll
      for (int j = 0; j < 4; ++j) a[i][j] = make_float4(0.f, 0.f, 0.f, 0.f);

#pragma unroll 5
    for (int n = 0; n < NTOP; ++n) {
      float4 pt = *(const float4*)&Ss[n * 132 + kq2];
      float4 pf = *(const float4*)&Ss[(40 + n) * 132 + kq2];
      float4 vt0 = *(const float4*)&Vs[n * 68 + ds8];
      float4 vt1 = *(const float4*)&Vs[n * 68 + ds8 + 4];
      float4 vf0 = *(const float4*)&Vs[(36 + n) * 68 + ds8];
      float4 vf1 = *(const float4*)&Vs[(36 + n) * 68 + ds8 + 4];
      FMA4(a[0][0], vt0, pt.x); FMA4(a[0][0], vf0, pf.x);
      FMA4(a[0][1], vt0, pt.y); FMA4(a[0][1], vf0, pf.y);
      FMA4(a[0][2], vt0, pt.z); FMA4(a[0][2], vf0, pf.z);
      FMA4(a[0][3], vt0, pt.w); FMA4(a[0][3], vf0, pf.w);
      FMA4(a[1][0], vt1, pt.x); FMA4(a[1][0], vf1, pf.x);
      FMA4(a[1][1], vt1, pt.y); FMA4(a[1][1], vf1, pf.y);
      FMA4(a[1][2], vt1, pt.z); FMA4(a[1][2], vf1, pf.z);
      FMA4(a[1][3], vt1, pt.w); FMA4(a[1][3], vf1, pf.w);
    }
    // transpose 4x4 sub-tiles (a[i][j] is float4 over d) -> float4 over k
    float* ob = out + (size_t)bh * (NE * LSEQ) + k0 + kq2;
#pragma unroll
    for (int i = 0; i < 2; ++i) {
      float4 o0 = make_float4(a[i][0].x, a[i][1].x, a[i][2].x, a[i][3].x);
      float4 o1 = make_float4(a[i][0].y, a[i][1].y, a[i][2].y, a[i][3].y);
      float4 o2 = make_float4(a[i][0].z, a[i][1].z, a[i][2].z, a[i][3].z);
      float4 o3 = make_float4(a[i][0].w, a[i][1].w, a[i][2].w, a[i][3].w);
      int d = ds8 + (i << 2);
      *(float4*)&ob[(size_t)(d + 0) * LSEQ] = o0;
      *(float4*)&ob[(size_t)(d + 1) * LSEQ] = o1;
      *(float4*)&ob[(size_t)(d + 2) * LSEQ] = o2;
      *(float4*)&ob[(size_t)(d + 3) * LSEQ] = o3;
    }
  }
}

// ---------------------------------------------------------------------------
extern "C" void kernel_launch(void* const* d_in, const int* in_sizes, int n_in,
                              void* d_out, int out_size, void* d_ws, size_t ws_size,
                              hipStream_t stream) {
  const float* tfq  = (const float*)d_in[0];
  const float* qm   = (const float*)d_in[1];
  const float* km   = (const float*)d_in[2];
  const float* vm   = (const float*)d_in[3];
  const float* mixw = (const float*)d_in[6];
  // d_in[4], d_in[5] (weights1_*), d_in[7] (mask), d_in[8] (mode_index):
  // dead code w.r.t. the returned output — skipped.

  float*  amp2   = (float*)d_ws;                 // 32*1024 f32
  float*  norms  = amp2 + 32 * LSEQ;             // 32*1024 f32
  int*    sel_t  = (int*)(norms + 32 * LSEQ);    // 32*35 i32
  int*    sel_tf = sel_t + 32 * NTOP;
  float2* twg    = (float2*)(sel_tf + 32 * NTOP + 13);  // 8B-aligned (pad 13)
  float*  out    = (float*)d_out;

  zero_kernel<<<dim3(128), dim3(256), 0, stream>>>(amp2, 32 * LSEQ);
  tw_kernel<<<dim3(2), dim3(256), 0, stream>>>(twg);
  norm_kernel<<<dim3(2048), dim3(256), 0, stream>>>(tfq, norms);
  corr_fft_kernel<<<dim3(1024), dim3(128), 0, stream>>>(qm, km, twg, amp2);
  topk_kernel<<<dim3(64), dim3(256), 0, stream>>>(amp2, norms, sel_t, sel_tf);
  attn_out_kernel<<<dim3(256), dim3(256), 0, stream>>>(qm, tfq, km, vm, mixw,
                                                       sel_t, sel_tf, out);
}

// Round 5
// 79.487 us; speedup vs baseline: 2.4709x; 1.1153x over previous
//
#include <hip/hip_runtime.h>

#define LSEQ 1024
#define NH 8
#define NE 64
#define NTOP 35
#define QKSCALE 0.04419417382415922f   // 1/sqrt(512)

typedef unsigned long long u64;

#define ZP(i) ((i) + ((i) >> 4))       // pad 1 float2 per 16 -> 1088 slots

#define FMA4(d, v, sc) \
  (d).x = fmaf((v).x, (sc), (d).x); (d).y = fmaf((v).y, (sc), (d).y); \
  (d).z = fmaf((v).z, (sc), (d).z); (d).w = fmaf((v).w, (sc), (d).w);

__device__ __forceinline__ float2 cadd(float2 a, float2 b) {
  return make_float2(a.x + b.x, a.y + b.y);
}
__device__ __forceinline__ float2 csub(float2 a, float2 b) {
  return make_float2(a.x - b.x, a.y - b.y);
}
__device__ __forceinline__ float2 cmul(float2 a, float2 w) {
  return make_float2(a.x * w.x - a.y * w.y, a.x * w.y + a.y * w.x);
}
__device__ __forceinline__ float2 cmulc(float2 a, float2 w) {  // a * conj(w)
  return make_float2(a.x * w.x + a.y * w.y, a.y * w.x - a.x * w.y);
}
// forward DIF radix-4 butterfly (w = e^{-2pi i/S})
__device__ __forceinline__ void btf4f(float2& x0, float2& x1, float2& x2,
                                      float2& x3, float2 w1, float2 w2,
                                      float2 w3) {
  float2 t0 = cadd(x0, x2), t1 = cadd(x1, x3), t2 = csub(x0, x2);
  float2 d = csub(x1, x3);
  float2 t3 = make_float2(d.y, -d.x);          // -i * d
  x0 = cadd(t0, t1);
  x1 = cmul(cadd(t2, t3), w1);
  x2 = cmul(csub(t0, t1), w2);
  x3 = cmul(csub(t2, t3), w3);
}
// inverse DIT radix-4 butterfly (exact per-stage inverse, scale 4/stage)
__device__ __forceinline__ void btf4i(float2& x0, float2& x1, float2& x2,
                                      float2& x3, float2 w1, float2 w2,
                                      float2 w3) {
  float2 b1 = cmulc(x1, w1), b2 = cmulc(x2, w2), b3 = cmulc(x3, w3);
  float2 A = cadd(x0, b2), B = csub(x0, b2);
  float2 C = cadd(b1, b3), D = csub(b1, b3);
  x0 = cadd(A, C);
  x1 = make_float2(B.x - D.y, B.y + D.x);      // B + iD
  x2 = csub(A, C);
  x3 = make_float2(B.x + D.y, B.y - D.x);      // B - iD
}
__device__ __forceinline__ int rev4(int p) {   // reverse 5 base-4 digits
  return ((p & 3) << 8) | (((p >> 2) & 3) << 6) | (((p >> 4) & 3) << 4) |
         (((p >> 6) & 3) << 2) | ((p >> 8) & 3);
}

// ---------------------------------------------------------------------------
// prep: tf row-norms (all blocks) + zero amp2 (blocks<128) + twiddle table
// (blocks 2040..2043). grid = 2048 x 256.
// ---------------------------------------------------------------------------
__global__ __launch_bounds__(256) void prep_kernel(
    const float* __restrict__ tfq, float* __restrict__ norms,
    float* __restrict__ amp2, float2* __restrict__ twg) {
  const int tid = threadIdx.x, bid = blockIdx.x;
  const int rid = bid * 16 + (tid >> 4);
  const int le = tid & 15;
  float4 v = *(const float4*)(tfq + (size_t)rid * NE + (le << 2));
  float s = v.x * v.x + v.y * v.y + v.z * v.z + v.w * v.w;
#pragma unroll
  for (int off = 8; off > 0; off >>= 1) s += __shfl_xor(s, off, 16);
  if (le == 0) {
    int b = rid >> 13, l = (rid >> 3) & 1023, h = rid & 7;
    norms[(size_t)(b * 8 + h) * LSEQ + l] = s;
  }
  if (bid < 128) {
    amp2[bid * 256 + tid] = 0.f;
  } else if (bid >= 2040 && bid < 2044) {
    int j = (bid - 2040) * 256 + tid;   // 0..1023
    float sn, cs;
    sincosf(6.283185307179586f * (float)j * (1.0f / 1024.0f), &sn, &cs);
    twg[j] = make_float2(cs, -sn);
  }
}

// ---------------------------------------------------------------------------
// Kernel A: circular cross-correlation amplitude^2 via packed radix-4 FFTs.
// One block per (bh, channel-pair). z_e = q_e + i*k_e; P = Q*conj(K) via
// Hermitian partners in the base-4 digit-reversed domain; Y = P0 + i*P1.
// First fwd stage (S=1024) + last inv stage are register-local (j-dim).
// ---------------------------------------------------------------------------
__global__ __launch_bounds__(128) void corr_fft_kernel(
    const float* __restrict__ qm, const float* __restrict__ km,
    const float2* __restrict__ twg, float* __restrict__ amp2) {
  const int tid  = threadIdx.x;
  const int bh   = blockIdx.x & 31;
  const int pair = blockIdx.x >> 5;
  const int b = bh >> 3, h = bh & 7;
  const size_t base = (size_t)b * (LSEQ * NH * NE) + (size_t)h * NE + (pair << 1);

  __shared__ float2 z0[1088];
  __shared__ float2 z1[1088];
  __shared__ float2 tw[1024];   // exp(-2*pi*i*j/1024)

  float2 a0[8], a1[8];
#pragma unroll
  for (int j = 0; j < 8; ++j) {
    int t = tid + (j << 7);
    float2 qv = *(const float2*)(qm + base + (size_t)t * (NH * NE));
    float2 kv = *(const float2*)(km + base + (size_t)t * (NH * NE));
    a0[j] = make_float2(qv.x, kv.x);
    a1[j] = make_float2(qv.y, kv.y);
  }
#pragma unroll
  for (int j = 0; j < 8; ++j) tw[tid + (j << 7)] = twg[tid + (j << 7)];
  __syncthreads();

  // forward stage 1 (S=1024) in registers: butterfly q = tid + 128*jj over
  // elements {q, q+256, q+512, q+768} = a[jj], a[jj+2], a[jj+4], a[jj+6]
#pragma unroll
  for (int jj = 0; jj < 2; ++jj) {
    int q = tid + (jj << 7);
    float2 w1 = tw[q], w2 = tw[2 * q], w3 = tw[3 * q];
    btf4f(a0[jj], a0[jj + 2], a0[jj + 4], a0[jj + 6], w1, w2, w3);
    btf4f(a1[jj], a1[jj + 2], a1[jj + 4], a1[jj + 6], w1, w2, w3);
  }
#pragma unroll
  for (int j = 0; j < 8; ++j) {
    int t = tid + (j << 7);
    z0[ZP(t)] = a0[j];
    z1[ZP(t)] = a1[j];
  }
  __syncthreads();

  // forward LDS stages: S = 256, 64, 16, 4
#pragma unroll
  for (int st = 0; st < 4; ++st) {
    const int l2h = 6 - 2 * st, l2S = 8 - 2 * st, sc = 2 + 2 * st;
    const int hh = 1 << l2h;
#pragma unroll
    for (int jj = 0; jj < 2; ++jj) {
      int bb = tid + (jj << 7);
      int q = bb & (hh - 1);
      int idx = ((bb >> l2h) << l2S) + q;
      int e1 = q << sc;
      float2 w1 = tw[e1], w2 = tw[2 * e1], w3 = tw[3 * e1];
      int i0 = ZP(idx), i1 = ZP(idx + hh), i2 = ZP(idx + 2 * hh),
          i3 = ZP(idx + 3 * hh);
      float2 x0 = z0[i0], x1 = z0[i1], x2 = z0[i2], x3 = z0[i3];
      btf4f(x0, x1, x2, x3, w1, w2, w3);
      z0[i0] = x0; z0[i1] = x1; z0[i2] = x2; z0[i3] = x3;
      x0 = z1[i0]; x1 = z1[i1]; x2 = z1[i2]; x3 = z1[i3];
      btf4f(x0, x1, x2, x3, w1, w2, w3);
      z1[i0] = x0; z1[i1] = x1; z1[i2] = x2; z1[i3] = x3;
    }
    __syncthreads();
  }

  // pointwise: P = Q*conj(K) per channel; pack Y = P0 + i*P1 (digit-rev dom.)
  float2 yv[8];
#pragma unroll
  for (int j = 0; j < 8; ++j) {
    int p = tid + (j << 7);
    int f = rev4(p);
    int fm = (1024 - f) & 1023;
    int pm = rev4(fm);
    float2 A0 = z0[ZP(p)], B0 = z0[ZP(pm)];
    float2 A1 = z1[ZP(p)], B1 = z1[ZP(pm)];
    float2 Q0 = make_float2(0.5f * (A0.x + B0.x), 0.5f * (A0.y - B0.y));
    float2 iK0 = make_float2(0.5f * (A0.x - B0.x), 0.5f * (A0.y + B0.y));
    float2 K0 = make_float2(iK0.y, -iK0.x);
    float2 P0 = make_float2(Q0.x * K0.x + Q0.y * K0.y,
                            Q0.y * K0.x - Q0.x * K0.y);
    float2 Q1 = make_float2(0.5f * (A1.x + B1.x), 0.5f * (A1.y - B1.y));
    float2 iK1 = make_float2(0.5f * (A1.x - B1.x), 0.5f * (A1.y + B1.y));
    float2 K1 = make_float2(iK1.y, -iK1.x);
    float2 P1 = make_float2(Q1.x * K1.x + Q1.y * K1.y,
                            Q1.y * K1.x - Q1.x * K1.y);
    yv[j] = make_float2(P0.x - P1.y, P0.y + P1.x);
  }
  __syncthreads();
#pragma unroll
  for (int j = 0; j < 8; ++j) z0[ZP(tid + (j << 7))] = yv[j];
  __syncthreads();

  // inverse LDS stages: S = 4, 16, 64, 256
#pragma unroll
  for (int st = 0; st < 4; ++st) {
    const int l2h = 2 * st, l2S = 2 * st + 2, sc = 8 - 2 * st;
    const int hh = 1 << l2h;
#pragma unroll
    for (int jj = 0; jj < 2; ++jj) {
      int bb = tid + (jj << 7);
      int q = bb & (hh - 1);
      int idx = ((bb >> l2h) << l2S) + q;
      int e1 = q << sc;
      float2 w1 = tw[e1], w2 = tw[2 * e1], w3 = tw[3 * e1];
      int i0 = ZP(idx), i1 = ZP(idx + hh), i2 = ZP(idx + 2 * hh),
          i3 = ZP(idx + 3 * hh);
      float2 x0 = z0[i0], x1 = z0[i1], x2 = z0[i2], x3 = z0[i3];
      btf4i(x0, x1, x2, x3, w1, w2, w3);
      z0[i0] = x0; z0[i1] = x1; z0[i2] = x2; z0[i3] = x3;
    }
    __syncthreads();
  }

  // final inverse stage (S=1024) in registers, then |y|^2
#pragma unroll
  for (int j = 0; j < 8; ++j) a0[j] = z0[ZP(tid + (j << 7))];
#pragma unroll
  for (int jj = 0; jj < 2; ++jj) {
    int q = tid + (jj << 7);
    float2 w1 = tw[q], w2 = tw[2 * q], w3 = tw[3 * q];
    btf4i(a0[jj], a0[jj + 2], a0[jj + 4], a0[jj + 6], w1, w2, w3);
  }
  const float inv = 1.0f / 1024.0f;
#pragma unroll
  for (int j = 0; j < 8; ++j) {
    int t = tid + (j << 7);
    float2 y = a0[j];
    atomicAdd(&amp2[(size_t)bh * LSEQ + t],
              (y.x * y.x + y.y * y.y) * inv * inv);
  }
}

// ---------------------------------------------------------------------------
// Kernel B: top-35 per (bh, branch). u64 keys reproduce lax.top_k tie-break.
// ---------------------------------------------------------------------------
__global__ __launch_bounds__(256) void topk_kernel(
    const float* __restrict__ amp2, const float* __restrict__ norms,
    int* __restrict__ sel_t, int* __restrict__ sel_tf) {
  __shared__ u64 cand[4 * NTOP];
  const int tid = threadIdx.x;
  const int bh = blockIdx.x & 31;
  const int arr = blockIdx.x >> 5;
  const float* sc = (arr == 0 ? amp2 : norms) + (size_t)bh * LSEQ;
  int* sel = (arr == 0 ? sel_t : sel_tf) + bh * NTOP;

  const int wid = tid >> 6, lane = tid & 63;
  const int kb = wid << 8;
  u64 k0, k1, k2, k3;
  {
    int l;
    l = kb + lane;
    k0 = ((u64)__float_as_uint(sc[l]) << 32) | (unsigned)(LSEQ - 1 - l);
    l = kb + 64 + lane;
    k1 = ((u64)__float_as_uint(sc[l]) << 32) | (unsigned)(LSEQ - 1 - l);
    l = kb + 128 + lane;
    k2 = ((u64)__float_as_uint(sc[l]) << 32) | (unsigned)(LSEQ - 1 - l);
    l = kb + 192 + lane;
    k3 = ((u64)__float_as_uint(sc[l]) << 32) | (unsigned)(LSEQ - 1 - l);
  }
  for (int it = 0; it < NTOP; ++it) {
    u64 m01 = k0 > k1 ? k0 : k1;
    u64 m23 = k2 > k3 ? k2 : k3;
    u64 m = m01 > m23 ? m01 : m23;
#pragma unroll
    for (int off = 32; off > 0; off >>= 1) {
      u64 o = __shfl_xor(m, off);
      m = o > m ? o : m;
    }
    if (k0 == m) k0 = 0;
    else if (k1 == m) k1 = 0;
    else if (k2 == m) k2 = 0;
    else if (k3 == m) k3 = 0;
    if (lane == 0) cand[wid * NTOP + it] = m;
  }
  __syncthreads();

  if (tid < 64) {
    u64 c0 = (tid < 4 * NTOP) ? cand[tid] : 0;
    u64 c1 = (tid + 64 < 4 * NTOP) ? cand[tid + 64] : 0;
    u64 c2 = (tid + 128 < 4 * NTOP) ? cand[tid + 128] : 0;
    for (int it = 0; it < NTOP; ++it) {
      u64 m01 = c0 > c1 ? c0 : c1;
      u64 m = m01 > c2 ? m01 : c2;
#pragma unroll
      for (int off = 32; off > 0; off >>= 1) {
        u64 o = __shfl_xor(m, off);
        m = o > m ? o : m;
      }
      if (c0 == m) c0 = 0;
      else if (c1 == m) c1 = 0;
      else if (c2 == m) c2 = 0;
      if (tid == 0) sel[it] = (LSEQ - 1) - (int)(m & 0xffffffffULL);
    }
  }
}

// ---------------------------------------------------------------------------
// Kernel C v4: one score-GEMM pass over both branches (X for K and tfq both
// staged), thread tile 5 rows x 8 keys; per-key softmax+mix; PV 4d x 8k.
// Per block: (bh, 128-key chunk); 3 __syncthreads total. LDS ~147.6 KB.
// ---------------------------------------------------------------------------
__global__ __launch_bounds__(256) void attn_out_kernel(
    const float* __restrict__ qm, const float* __restrict__ tfq,
    const float* __restrict__ km, const float* __restrict__ vm,
    const float* __restrict__ mixw,
    const int* __restrict__ sel_t, const int* __restrict__ sel_tf,
    float* __restrict__ out) {
  __shared__ float Qs[2 * 40 * 68];    // 21.3 KB  [gr][68]
  __shared__ float Xs[2 * 64 * 132];   // 66.0 KB  [br][e][132]
  __shared__ float Ss[2 * 40 * 132];   // 41.3 KB  [gr][132]
  __shared__ float Vs[2 * 36 * 68];    // 19.1 KB

  const int tid = threadIdx.x;
  const int kc = blockIdx.x & 7;
  const int bh = blockIdx.x >> 3;
  const int b = bh >> 3, h = bh & 7;
  const int k0 = kc << 7;
  const size_t base = (size_t)b * (LSEQ * NH * NE) + (size_t)h * NE;

  // ---- stage Q (80 rows: br0 0..39, br1 40..79; rows >=35 per br zeroed) ----
  for (int i = tid; i < 1280; i += 256) {
    int r = i >> 4, e4 = (i & 15) << 2;
    int br = (r >= 40), n = r - (br ? 40 : 0);
    float4 v = make_float4(0.f, 0.f, 0.f, 0.f);
    if (n < NTOP) {
      int l = (br ? sel_tf : sel_t)[bh * NTOP + n];
      v = *(const float4*)((br ? tfq : qm) + base + (size_t)l * (NH * NE) + e4);
    }
    *(float4*)&Qs[r * 68 + e4] = v;
  }
  // ---- stage V ----
  for (int i = tid; i < 1152; i += 256) {
    int r = i >> 4, e4 = (i & 15) << 2;
    int br = (r >= 36), n = r - (br ? 36 : 0);
    float4 v = make_float4(0.f, 0.f, 0.f, 0.f);
    if (n < NTOP) {
      int l = (br ? sel_tf : sel_t)[bh * NTOP + n];
      v = *(const float4*)(vm + base + (size_t)l * (NH * NE) + e4);
    }
    *(float4*)&Vs[r * 68 + e4] = v;
  }
  // ---- stage X transposed, both branches ----
  for (int i = tid; i < 4096; i += 256) {
    int br = i >> 11, k = (i >> 4) & 127, e4 = (i & 15) << 2;
    const float* xsrc = br ? tfq : km;
    float4 v = *(const float4*)(xsrc + base + (size_t)(k0 + k) * (NH * NE) + e4);
    float* X = Xs + br * (64 * 132);
    X[(e4 + 0) * 132 + k] = v.x;
    X[(e4 + 1) * 132 + k] = v.y;
    X[(e4 + 2) * 132 + k] = v.z;
    X[(e4 + 3) * 132 + k] = v.w;
  }
  __syncthreads();

  // ---- score GEMM: strip s = tid>>4 (5 rows), 8 keys ----
  {
    const int s = tid >> 4;
    const int kq8 = (tid & 15) << 3;
    const float* Xb = Xs + (s >> 3) * (64 * 132);
    float4 acc[5][2];
#pragma unroll
    for (int r = 0; r < 5; ++r) {
      acc[r][0] = make_float4(0.f, 0.f, 0.f, 0.f);
      acc[r][1] = make_float4(0.f, 0.f, 0.f, 0.f);
    }
    for (int e0 = 0; e0 < NE; e0 += 4) {
      float4 xv[4][2];
#pragma unroll
      for (int m = 0; m < 4; ++m) {
        xv[m][0] = *(const float4*)&Xb[(e0 + m) * 132 + kq8];
        xv[m][1] = *(const float4*)&Xb[(e0 + m) * 132 + kq8 + 4];
      }
#pragma unroll
      for (int r = 0; r < 5; ++r) {
        float4 qv = *(const float4*)&Qs[(s * 5 + r) * 68 + e0];
        FMA4(acc[r][0], xv[0][0], qv.x); FMA4(acc[r][1], xv[0][1], qv.x);
        FMA4(acc[r][0], xv[1][0], qv.y); FMA4(acc[r][1], xv[1][1], qv.y);
        FMA4(acc[r][0], xv[2][0], qv.z); FMA4(acc[r][1], xv[2][1], qv.z);
        FMA4(acc[r][0], xv[3][0], qv.w); FMA4(acc[r][1], xv[3][1], qv.w);
      }
    }
#pragma unroll
    for (int r = 0; r < 5; ++r) {
      *(float4*)&Ss[(s * 5 + r) * 132 + kq8] = acc[r][0];
      *(float4*)&Ss[(s * 5 + r) * 132 + kq8 + 4] = acc[r][1];
    }
  }
  __syncthreads();

  // ---- per-key softmax over 35 rows + mix coefficient (both branches) ----
  {
    const int k = tid & 127, br = tid >> 7;
    float p[NTOP];
    float mx = -1e30f;
#pragma unroll
    for (int n = 0; n < NTOP; ++n) {
      p[n] = Ss[(br * 40 + n) * 132 + k] * QKSCALE;
      mx = fmaxf(mx, p[n]);
    }
    float sum = 0.f;
#pragma unroll
    for (int n = 0; n < NTOP; ++n) { p[n] = __expf(p[n] - mx); sum += p[n]; }
    const float w0 = mixw[(size_t)h * (LSEQ * 2) + (size_t)(k0 + k) * 2 + 0];
    const float w1 = mixw[(size_t)h * (LSEQ * 2) + (size_t)(k0 + k) * 2 + 1];
    const float ew0 = __expf(w0), ew1 = __expf(w1);
    const float c = (br ? ew1 : ew0) / ((ew0 + ew1) * sum);
#pragma unroll
    for (int n = 0; n < NTOP; ++n) Ss[(br * 40 + n) * 132 + k] = p[n] * c;
  }
  __syncthreads();

  // ---- PV GEMM: 4d x 8k per thread, both branches accumulated ----
  {
    const int kq8 = (tid & 15) << 3;
    const int d0 = (tid >> 4) << 2;
    float4 a[4][2];
#pragma unroll
    for (int dj = 0; dj < 4; ++dj) {
      a[dj][0] = make_float4(0.f, 0.f, 0.f, 0.f);
      a[dj][1] = make_float4(0.f, 0.f, 0.f, 0.f);
    }
#pragma unroll 5
    for (int n = 0; n < NTOP; ++n) {
      float4 p0 = *(const float4*)&Ss[n * 132 + kq8];
      float4 p1 = *(const float4*)&Ss[n * 132 + kq8 + 4];
      float4 vv = *(const float4*)&Vs[n * 68 + d0];
      FMA4(a[0][0], p0, vv.x); FMA4(a[0][1], p1, vv.x);
      FMA4(a[1][0], p0, vv.y); FMA4(a[1][1], p1, vv.y);
      FMA4(a[2][0], p0, vv.z); FMA4(a[2][1], p1, vv.z);
      FMA4(a[3][0], p0, vv.w); FMA4(a[3][1], p1, vv.w);
    }
#pragma unroll 5
    for (int n = 0; n < NTOP; ++n) {
      float4 p0 = *(const float4*)&Ss[(40 + n) * 132 + kq8];
      float4 p1 = *(const float4*)&Ss[(40 + n) * 132 + kq8 + 4];
      float4 vv = *(const float4*)&Vs[(36 + n) * 68 + d0];
      FMA4(a[0][0], p0, vv.x); FMA4(a[0][1], p1, vv.x);
      FMA4(a[1][0], p0, vv.y); FMA4(a[1][1], p1, vv.y);
      FMA4(a[2][0], p0, vv.z); FMA4(a[2][1], p1, vv.z);
      FMA4(a[3][0], p0, vv.w); FMA4(a[3][1], p1, vv.w);
    }
    float* ob = out + (size_t)bh * (NE * LSEQ) + k0 + kq8;
#pragma unroll
    for (int dj = 0; dj < 4; ++dj) {
      *(float4*)&ob[(size_t)(d0 + dj) * LSEQ] = a[dj][0];
      *(float4*)&ob[(size_t)(d0 + dj) * LSEQ + 4] = a[dj][1];
    }
  }
}

// ---------------------------------------------------------------------------
extern "C" void kernel_launch(void* const* d_in, const int* in_sizes, int n_in,
                              void* d_out, int out_size, void* d_ws, size_t ws_size,
                              hipStream_t stream) {
  const float* tfq  = (const float*)d_in[0];
  const float* qm   = (const float*)d_in[1];
  const float* km   = (const float*)d_in[2];
  const float* vm   = (const float*)d_in[3];
  const float* mixw = (const float*)d_in[6];
  // d_in[4], d_in[5] (weights1_*), d_in[7] (mask), d_in[8] (mode_index):
  // dead code w.r.t. the returned output — skipped.

  float2* twg    = (float2*)d_ws;                  // 1024 float2 (8B aligned)
  float*  amp2   = (float*)(twg + 1024);           // 32*1024 f32
  float*  norms  = amp2 + 32 * LSEQ;               // 32*1024 f32
  int*    sel_t  = (int*)(norms + 32 * LSEQ);      // 32*35 i32
  int*    sel_tf = sel_t + 32 * NTOP;
  float*  out    = (float*)d_out;

  prep_kernel<<<dim3(2048), dim3(256), 0, stream>>>(tfq, norms, amp2, twg);
  corr_fft_kernel<<<dim3(1024), dim3(128), 0, stream>>>(qm, km, twg, amp2);
  topk_kernel<<<dim3(64), dim3(256), 0, stream>>>(amp2, norms, sel_t, sel_tf);
  attn_out_kernel<<<dim3(256), dim3(256), 0, stream>>>(qm, tfq, km, vm, mixw,
                                                       sel_t, sel_tf, out);
}

// Round 6
// 70.206 us; speedup vs baseline: 2.7976x; 1.1322x over previous
//
#include <hip/hip_runtime.h>

#define LSEQ 1024
#define NH 8
#define NE 64
#define NTOP 35
#define QKSCALE 0.04419417382415922f   // 1/sqrt(512)

typedef unsigned long long u64;

#define ZP(i) ((i) + ((i) >> 4))       // pad 1 float2 per 16 -> 1088 slots

#define FMA4(d, v, sc) \
  (d).x = fmaf((v).x, (sc), (d).x); (d).y = fmaf((v).y, (sc), (d).y); \
  (d).z = fmaf((v).z, (sc), (d).z); (d).w = fmaf((v).w, (sc), (d).w);

__device__ __forceinline__ float2 cadd(float2 a, float2 b) {
  return make_float2(a.x + b.x, a.y + b.y);
}
__device__ __forceinline__ float2 csub(float2 a, float2 b) {
  return make_float2(a.x - b.x, a.y - b.y);
}
__device__ __forceinline__ float2 cmul(float2 a, float2 w) {
  return make_float2(a.x * w.x - a.y * w.y, a.x * w.y + a.y * w.x);
}
__device__ __forceinline__ float2 cmulc(float2 a, float2 w) {  // a * conj(w)
  return make_float2(a.x * w.x + a.y * w.y, a.y * w.x - a.x * w.y);
}
// forward DIF radix-4 butterfly (w = e^{-2pi i/S})
__device__ __forceinline__ void btf4f(float2& x0, float2& x1, float2& x2,
                                      float2& x3, float2 w1, float2 w2,
                                      float2 w3) {
  float2 t0 = cadd(x0, x2), t1 = cadd(x1, x3), t2 = csub(x0, x2);
  float2 d = csub(x1, x3);
  float2 t3 = make_float2(d.y, -d.x);          // -i * d
  x0 = cadd(t0, t1);
  x1 = cmul(cadd(t2, t3), w1);
  x2 = cmul(csub(t0, t1), w2);
  x3 = cmul(csub(t2, t3), w3);
}
// inverse DIT radix-4 butterfly (exact per-stage inverse, scale 4/stage)
__device__ __forceinline__ void btf4i(float2& x0, float2& x1, float2& x2,
                                      float2& x3, float2 w1, float2 w2,
                                      float2 w3) {
  float2 b1 = cmulc(x1, w1), b2 = cmulc(x2, w2), b3 = cmulc(x3, w3);
  float2 A = cadd(x0, b2), B = csub(x0, b2);
  float2 C = cadd(b1, b3), D = csub(b1, b3);
  x0 = cadd(A, C);
  x1 = make_float2(B.x - D.y, B.y + D.x);      // B + iD
  x2 = csub(A, C);
  x3 = make_float2(B.x + D.y, B.y - D.x);      // B - iD
}
__device__ __forceinline__ int rev4(int p) {   // reverse 5 base-4 digits
  return ((p & 3) << 8) | (((p >> 2) & 3) << 6) | (((p >> 4) & 3) << 4) |
         (((p >> 6) & 3) << 2) | ((p >> 8) & 3);
}

// ---------------------------------------------------------------------------
// prep: tf row-norms (all blocks) + zero amp2 (blocks<128) + twiddle table
// (blocks 2040..2043). grid = 2048 x 256.
// ---------------------------------------------------------------------------
__global__ __launch_bounds__(256) void prep_kernel(
    const float* __restrict__ tfq, float* __restrict__ norms,
    float* __restrict__ amp2, float2* __restrict__ twg) {
  const int tid = threadIdx.x, bid = blockIdx.x;
  const int rid = bid * 16 + (tid >> 4);
  const int le = tid & 15;
  float4 v = *(const float4*)(tfq + (size_t)rid * NE + (le << 2));
  float s = v.x * v.x + v.y * v.y + v.z * v.z + v.w * v.w;
#pragma unroll
  for (int off = 8; off > 0; off >>= 1) s += __shfl_xor(s, off, 16);
  if (le == 0) {
    int b = rid >> 13, l = (rid >> 3) & 1023, h = rid & 7;
    norms[(size_t)(b * 8 + h) * LSEQ + l] = s;
  }
  if (bid < 128) {
    amp2[bid * 256 + tid] = 0.f;
  } else if (bid >= 2040 && bid < 2044) {
    int j = (bid - 2040) * 256 + tid;   // 0..1023
    float sn, cs;
    sincosf(6.283185307179586f * (float)j * (1.0f / 1024.0f), &sn, &cs);
    twg[j] = make_float2(cs, -sn);
  }
}

// ---------------------------------------------------------------------------
// Kernel A: circular cross-correlation amplitude^2 via packed radix-4 FFTs.
// 256 threads, 4 elements/thread (was 128/8) -> 16 waves/CU = 4/SIMD.
// ---------------------------------------------------------------------------
__global__ __launch_bounds__(256) void corr_fft_kernel(
    const float* __restrict__ qm, const float* __restrict__ km,
    const float2* __restrict__ twg, float* __restrict__ amp2) {
  const int tid  = threadIdx.x;
  const int bh   = blockIdx.x & 31;
  const int pair = blockIdx.x >> 5;
  const int b = bh >> 3, h = bh & 7;
  const size_t base = (size_t)b * (LSEQ * NH * NE) + (size_t)h * NE + (pair << 1);

  __shared__ float2 z0[1088];
  __shared__ float2 z1[1088];
  __shared__ float2 tw[1024];   // exp(-2*pi*i*j/1024)

  float2 a0[4], a1[4];
#pragma unroll
  for (int j = 0; j < 4; ++j) {
    int t = tid + (j << 8);
    float2 qv = *(const float2*)(qm + base + (size_t)t * (NH * NE));
    float2 kv = *(const float2*)(km + base + (size_t)t * (NH * NE));
    a0[j] = make_float2(qv.x, kv.x);
    a1[j] = make_float2(qv.y, kv.y);
  }
#pragma unroll
  for (int j = 0; j < 4; ++j) tw[tid + (j << 8)] = twg[tid + (j << 8)];
  __syncthreads();

  // forward stage 1 (S=1024) in registers: q = tid over {q,q+256,q+512,q+768}
  {
    float2 w1 = tw[tid], w2 = tw[2 * tid], w3 = tw[3 * tid];
    btf4f(a0[0], a0[1], a0[2], a0[3], w1, w2, w3);
    btf4f(a1[0], a1[1], a1[2], a1[3], w1, w2, w3);
  }
#pragma unroll
  for (int j = 0; j < 4; ++j) {
    int t = tid + (j << 8);
    z0[ZP(t)] = a0[j];
    z1[ZP(t)] = a1[j];
  }
  __syncthreads();

  // forward LDS stages: S = 256, 64, 16, 4 (one butterfly/thread/array)
#pragma unroll
  for (int st = 0; st < 4; ++st) {
    const int l2h = 6 - 2 * st, l2S = 8 - 2 * st, sc = 2 + 2 * st;
    const int hh = 1 << l2h;
    const int q = tid & (hh - 1);
    const int idx = ((tid >> l2h) << l2S) + q;
    const int e1 = q << sc;
    float2 w1 = tw[e1], w2 = tw[2 * e1], w3 = tw[3 * e1];
    int i0 = ZP(idx), i1 = ZP(idx + hh), i2 = ZP(idx + 2 * hh),
        i3 = ZP(idx + 3 * hh);
    float2 x0 = z0[i0], x1 = z0[i1], x2 = z0[i2], x3 = z0[i3];
    btf4f(x0, x1, x2, x3, w1, w2, w3);
    z0[i0] = x0; z0[i1] = x1; z0[i2] = x2; z0[i3] = x3;
    x0 = z1[i0]; x1 = z1[i1]; x2 = z1[i2]; x3 = z1[i3];
    btf4f(x0, x1, x2, x3, w1, w2, w3);
    z1[i0] = x0; z1[i1] = x1; z1[i2] = x2; z1[i3] = x3;
    __syncthreads();
  }

  // pointwise: P = Q*conj(K) per channel; pack Y = P0 + i*P1 (digit-rev dom.)
  float2 yv[4];
#pragma unroll
  for (int j = 0; j < 4; ++j) {
    int p = tid + (j << 8);
    int f = rev4(p);
    int fm = (1024 - f) & 1023;
    int pm = rev4(fm);
    float2 A0 = z0[ZP(p)], B0 = z0[ZP(pm)];
    float2 A1 = z1[ZP(p)], B1 = z1[ZP(pm)];
    float2 Q0 = make_float2(0.5f * (A0.x + B0.x), 0.5f * (A0.y - B0.y));
    float2 iK0 = make_float2(0.5f * (A0.x - B0.x), 0.5f * (A0.y + B0.y));
    float2 K0 = make_float2(iK0.y, -iK0.x);
    float2 P0 = make_float2(Q0.x * K0.x + Q0.y * K0.y,
                            Q0.y * K0.x - Q0.x * K0.y);
    float2 Q1 = make_float2(0.5f * (A1.x + B1.x), 0.5f * (A1.y - B1.y));
    float2 iK1 = make_float2(0.5f * (A1.x - B1.x), 0.5f * (A1.y + B1.y));
    float2 K1 = make_float2(iK1.y, -iK1.x);
    float2 P1 = make_float2(Q1.x * K1.x + Q1.y * K1.y,
                            Q1.y * K1.x - Q1.x * K1.y);
    yv[j] = make_float2(P0.x - P1.y, P0.y + P1.x);
  }
  __syncthreads();
#pragma unroll
  for (int j = 0; j < 4; ++j) z0[ZP(tid + (j << 8))] = yv[j];
  __syncthreads();

  // inverse LDS stages: S = 4, 16, 64, 256
#pragma unroll
  for (int st = 0; st < 4; ++st) {
    const int l2h = 2 * st, l2S = 2 * st + 2, sc = 8 - 2 * st;
    const int hh = 1 << l2h;
    const int q = tid & (hh - 1);
    const int idx = ((tid >> l2h) << l2S) + q;
    const int e1 = q << sc;
    float2 w1 = tw[e1], w2 = tw[2 * e1], w3 = tw[3 * e1];
    int i0 = ZP(idx), i1 = ZP(idx + hh), i2 = ZP(idx + 2 * hh),
        i3 = ZP(idx + 3 * hh);
    float2 x0 = z0[i0], x1 = z0[i1], x2 = z0[i2], x3 = z0[i3];
    btf4i(x0, x1, x2, x3, w1, w2, w3);
    z0[i0] = x0; z0[i1] = x1; z0[i2] = x2; z0[i3] = x3;
    __syncthreads();
  }

  // final inverse stage (S=1024) in registers, then |y|^2
#pragma unroll
  for (int j = 0; j < 4; ++j) a0[j] = z0[ZP(tid + (j << 8))];
  {
    float2 w1 = tw[tid], w2 = tw[2 * tid], w3 = tw[3 * tid];
    btf4i(a0[0], a0[1], a0[2], a0[3], w1, w2, w3);
  }
  const float inv = 1.0f / 1024.0f;
#pragma unroll
  for (int j = 0; j < 4; ++j) {
    int t = tid + (j << 8);
    float2 y = a0[j];
    atomicAdd(&amp2[(size_t)bh * LSEQ + t],
              (y.x * y.x + y.y * y.y) * inv * inv);
  }
}

// ---------------------------------------------------------------------------
// Kernel B: top-35 per (bh, branch). u64 keys reproduce lax.top_k tie-break.
// ---------------------------------------------------------------------------
__global__ __launch_bounds__(256) void topk_kernel(
    const float* __restrict__ amp2, const float* __restrict__ norms,
    int* __restrict__ sel_t, int* __restrict__ sel_tf) {
  __shared__ u64 cand[4 * NTOP];
  const int tid = threadIdx.x;
  const int bh = blockIdx.x & 31;
  const int arr = blockIdx.x >> 5;
  const float* sc = (arr == 0 ? amp2 : norms) + (size_t)bh * LSEQ;
  int* sel = (arr == 0 ? sel_t : sel_tf) + bh * NTOP;

  const int wid = tid >> 6, lane = tid & 63;
  const int kb = wid << 8;
  u64 k0, k1, k2, k3;
  {
    int l;
    l = kb + lane;
    k0 = ((u64)__float_as_uint(sc[l]) << 32) | (unsigned)(LSEQ - 1 - l);
    l = kb + 64 + lane;
    k1 = ((u64)__float_as_uint(sc[l]) << 32) | (unsigned)(LSEQ - 1 - l);
    l = kb + 128 + lane;
    k2 = ((u64)__float_as_uint(sc[l]) << 32) | (unsigned)(LSEQ - 1 - l);
    l = kb + 192 + lane;
    k3 = ((u64)__float_as_uint(sc[l]) << 32) | (unsigned)(LSEQ - 1 - l);
  }
  for (int it = 0; it < NTOP; ++it) {
    u64 m01 = k0 > k1 ? k0 : k1;
    u64 m23 = k2 > k3 ? k2 : k3;
    u64 m = m01 > m23 ? m01 : m23;
#pragma unroll
    for (int off = 32; off > 0; off >>= 1) {
      u64 o = __shfl_xor(m, off);
      m = o > m ? o : m;
    }
    if (k0 == m) k0 = 0;
    else if (k1 == m) k1 = 0;
    else if (k2 == m) k2 = 0;
    else if (k3 == m) k3 = 0;
    if (lane == 0) cand[wid * NTOP + it] = m;
  }
  __syncthreads();

  if (tid < 64) {
    u64 c0 = (tid < 4 * NTOP) ? cand[tid] : 0;
    u64 c1 = (tid + 64 < 4 * NTOP) ? cand[tid + 64] : 0;
    u64 c2 = (tid + 128 < 4 * NTOP) ? cand[tid + 128] : 0;
    for (int it = 0; it < NTOP; ++it) {
      u64 m01 = c0 > c1 ? c0 : c1;
      u64 m = m01 > c2 ? m01 : c2;
#pragma unroll
      for (int off = 32; off > 0; off >>= 1) {
        u64 o = __shfl_xor(m, off);
        m = o > m ? o : m;
      }
      if (c0 == m) c0 = 0;
      else if (c1 == m) c1 = 0;
      else if (c2 == m) c2 = 0;
      if (tid == 0) sel[it] = (LSEQ - 1) - (int)(m & 0xffffffffULL);
    }
  }
}

// ---------------------------------------------------------------------------
// Kernel C v5: same phases as v4 but 512 threads (8 waves = 2/SIMD).
// Score GEMM: 16 strips x 5 rows, 32 key-groups x 4 keys.
// PV GEMM: 16 d-groups x 4d, 32 key-groups x 4k.
// ---------------------------------------------------------------------------
__global__ __launch_bounds__(512) void attn_out_kernel(
    const float* __restrict__ qm, const float* __restrict__ tfq,
    const float* __restrict__ km, const float* __restrict__ vm,
    const float* __restrict__ mixw,
    const int* __restrict__ sel_t, const int* __restrict__ sel_tf,
    float* __restrict__ out) {
  __shared__ float Qs[2 * 40 * 68];    // 21.3 KB  [gr][68]
  __shared__ float Xs[2 * 64 * 132];   // 66.0 KB  [br][e][132]
  __shared__ float Ss[2 * 40 * 132];   // 41.3 KB  [gr][132]
  __shared__ float Vs[2 * 36 * 68];    // 19.1 KB

  const int tid = threadIdx.x;
  const int kc = blockIdx.x & 7;
  const int bh = blockIdx.x >> 3;
  const int b = bh >> 3, h = bh & 7;
  const int k0 = kc << 7;
  const size_t base = (size_t)b * (LSEQ * NH * NE) + (size_t)h * NE;

  // ---- stage Q (80 rows: br0 0..39, br1 40..79; rows >=35 per br zeroed) ----
  for (int i = tid; i < 1280; i += 512) {
    int r = i >> 4, e4 = (i & 15) << 2;
    int br = (r >= 40), n = r - (br ? 40 : 0);
    float4 v = make_float4(0.f, 0.f, 0.f, 0.f);
    if (n < NTOP) {
      int l = (br ? sel_tf : sel_t)[bh * NTOP + n];
      v = *(const float4*)((br ? tfq : qm) + base + (size_t)l * (NH * NE) + e4);
    }
    *(float4*)&Qs[r * 68 + e4] = v;
  }
  // ---- stage V ----
  for (int i = tid; i < 1152; i += 512) {
    int r = i >> 4, e4 = (i & 15) << 2;
    int br = (r >= 36), n = r - (br ? 36 : 0);
    float4 v = make_float4(0.f, 0.f, 0.f, 0.f);
    if (n < NTOP) {
      int l = (br ? sel_tf : sel_t)[bh * NTOP + n];
      v = *(const float4*)(vm + base + (size_t)l * (NH * NE) + e4);
    }
    *(float4*)&Vs[r * 68 + e4] = v;
  }
  // ---- stage X transposed, both branches ----
  for (int i = tid; i < 4096; i += 512) {
    int br = i >> 11, k = (i >> 4) & 127, e4 = (i & 15) << 2;
    const float* xsrc = br ? tfq : km;
    float4 v = *(const float4*)(xsrc + base + (size_t)(k0 + k) * (NH * NE) + e4);
    float* X = Xs + br * (64 * 132);
    X[(e4 + 0) * 132 + k] = v.x;
    X[(e4 + 1) * 132 + k] = v.y;
    X[(e4 + 2) * 132 + k] = v.z;
    X[(e4 + 3) * 132 + k] = v.w;
  }
  __syncthreads();

  // ---- score GEMM: strip s = tid>>5 (5 rows), 4 keys ----
  {
    const int s = tid >> 5;            // 0..15 (0-7 br0, 8-15 br1)
    const int kq4 = (tid & 31) << 2;   // 0..124
    const float* Xb = Xs + (s >> 3) * (64 * 132);
    float4 acc[5];
#pragma unroll
    for (int r = 0; r < 5; ++r) acc[r] = make_float4(0.f, 0.f, 0.f, 0.f);
    for (int e0 = 0; e0 < NE; e0 += 4) {
      float4 xv0 = *(const float4*)&Xb[(e0 + 0) * 132 + kq4];
      float4 xv1 = *(const float4*)&Xb[(e0 + 1) * 132 + kq4];
      float4 xv2 = *(const float4*)&Xb[(e0 + 2) * 132 + kq4];
      float4 xv3 = *(const float4*)&Xb[(e0 + 3) * 132 + kq4];
#pragma unroll
      for (int r = 0; r < 5; ++r) {
        float4 qv = *(const float4*)&Qs[(s * 5 + r) * 68 + e0];
        FMA4(acc[r], xv0, qv.x);
        FMA4(acc[r], xv1, qv.y);
        FMA4(acc[r], xv2, qv.z);
        FMA4(acc[r], xv3, qv.w);
      }
    }
#pragma unroll
    for (int r = 0; r < 5; ++r)
      *(float4*)&Ss[(s * 5 + r) * 132 + kq4] = acc[r];
  }
  __syncthreads();

  // ---- per-key softmax over 35 rows + mix coefficient (both branches) ----
  if (tid < 256) {
    const int k = tid & 127, br = tid >> 7;
    float p[NTOP];
    float mx = -1e30f;
#pragma unroll
    for (int n = 0; n < NTOP; ++n) {
      p[n] = Ss[(br * 40 + n) * 132 + k] * QKSCALE;
      mx = fmaxf(mx, p[n]);
    }
    float sum = 0.f;
#pragma unroll
    for (int n = 0; n < NTOP; ++n) { p[n] = __expf(p[n] - mx); sum += p[n]; }
    const float w0 = mixw[(size_t)h * (LSEQ * 2) + (size_t)(k0 + k) * 2 + 0];
    const float w1 = mixw[(size_t)h * (LSEQ * 2) + (size_t)(k0 + k) * 2 + 1];
    const float ew0 = __expf(w0), ew1 = __expf(w1);
    const float c = (br ? ew1 : ew0) / ((ew0 + ew1) * sum);
#pragma unroll
    for (int n = 0; n < NTOP; ++n) Ss[(br * 40 + n) * 132 + k] = p[n] * c;
  }
  __syncthreads();

  // ---- PV GEMM: 4d x 4k per thread, both branches accumulated ----
  {
    const int kq4 = (tid & 31) << 2;   // 4 keys
    const int d0 = (tid >> 5) << 2;    // 4 d
    float4 a[4];
#pragma unroll
    for (int dj = 0; dj < 4; ++dj) a[dj] = make_float4(0.f, 0.f, 0.f, 0.f);
#pragma unroll 5
    for (int n = 0; n < NTOP; ++n) {
      float4 p0 = *(const float4*)&Ss[n * 132 + kq4];
      float4 vv = *(const float4*)&Vs[n * 68 + d0];
      FMA4(a[0], p0, vv.x);
      FMA4(a[1], p0, vv.y);
      FMA4(a[2], p0, vv.z);
      FMA4(a[3], p0, vv.w);
    }
#pragma unroll 5
    for (int n = 0; n < NTOP; ++n) {
      float4 p1 = *(const float4*)&Ss[(40 + n) * 132 + kq4];
      float4 vv = *(const float4*)&Vs[(36 + n) * 68 + d0];
      FMA4(a[0], p1, vv.x);
      FMA4(a[1], p1, vv.y);
      FMA4(a[2], p1, vv.z);
      FMA4(a[3], p1, vv.w);
    }
    float* ob = out + (size_t)bh * (NE * LSEQ) + k0 + kq4;
#pragma unroll
    for (int dj = 0; dj < 4; ++dj)
      *(float4*)&ob[(size_t)(d0 + dj) * LSEQ] = a[dj];
  }
}

// ---------------------------------------------------------------------------
extern "C" void kernel_launch(void* const* d_in, const int* in_sizes, int n_in,
                              void* d_out, int out_size, void* d_ws, size_t ws_size,
                              hipStream_t stream) {
  const float* tfq  = (const float*)d_in[0];
  const float* qm   = (const float*)d_in[1];
  const float* km   = (const float*)d_in[2];
  const float* vm   = (const float*)d_in[3];
  const float* mixw = (const float*)d_in[6];
  // d_in[4], d_in[5] (weights1_*), d_in[7] (mask), d_in[8] (mode_index):
  // dead code w.r.t. the returned output — skipped.

  float2* twg    = (float2*)d_ws;                  // 1024 float2 (8B aligned)
  float*  amp2   = (float*)(twg + 1024);           // 32*1024 f32
  float*  norms  = amp2 + 32 * LSEQ;               // 32*1024 f32
  int*    sel_t  = (int*)(norms + 32 * LSEQ);      // 32*35 i32
  int*    sel_tf = sel_t + 32 * NTOP;
  float*  out    = (float*)d_out;

  prep_kernel<<<dim3(2048), dim3(256), 0, stream>>>(tfq, norms, amp2, twg);
  corr_fft_kernel<<<dim3(1024), dim3(256), 0, stream>>>(qm, km, twg, amp2);
  topk_kernel<<<dim3(64), dim3(256), 0, stream>>>(amp2, norms, sel_t, sel_tf);
  attn_out_kernel<<<dim3(256), dim3(512), 0, stream>>>(qm, tfq, km, vm, mixw,
                                                       sel_t, sel_tf, out);
}

// Round 7
// 69.750 us; speedup vs baseline: 2.8159x; 1.0065x over previous
//
#include <hip/hip_runtime.h>

#define LSEQ 1024
#define NH 8
#define NE 64
#define NTOP 35
#define QKSCALE 0.04419417382415922f   // 1/sqrt(512)

typedef unsigned long long u64;

#define ZP(i) ((i) + ((i) >> 4))       // pad 1 float2 per 16 -> 1088 slots

#define FMA4(d, v, sc) \
  (d).x = fmaf((v).x, (sc), (d).x); (d).y = fmaf((v).y, (sc), (d).y); \
  (d).z = fmaf((v).z, (sc), (d).z); (d).w = fmaf((v).w, (sc), (d).w);

__device__ __forceinline__ float2 cadd(float2 a, float2 b) {
  return make_float2(a.x + b.x, a.y + b.y);
}
__device__ __forceinline__ float2 csub(float2 a, float2 b) {
  return make_float2(a.x - b.x, a.y - b.y);
}
__device__ __forceinline__ float2 cmul(float2 a, float2 w) {
  return make_float2(a.x * w.x - a.y * w.y, a.x * w.y + a.y * w.x);
}
__device__ __forceinline__ float2 cmulc(float2 a, float2 w) {  // a * conj(w)
  return make_float2(a.x * w.x + a.y * w.y, a.y * w.x - a.x * w.y);
}
// forward DIF radix-4 butterfly (w = e^{-2pi i/S})
__device__ __forceinline__ void btf4f(float2& x0, float2& x1, float2& x2,
                                      float2& x3, float2 w1, float2 w2,
                                      float2 w3) {
  float2 t0 = cadd(x0, x2), t1 = cadd(x1, x3), t2 = csub(x0, x2);
  float2 d = csub(x1, x3);
  float2 t3 = make_float2(d.y, -d.x);          // -i * d
  x0 = cadd(t0, t1);
  x1 = cmul(cadd(t2, t3), w1);
  x2 = cmul(csub(t0, t1), w2);
  x3 = cmul(csub(t2, t3), w3);
}
// inverse DIT radix-4 butterfly (exact per-stage inverse, scale 4/stage)
__device__ __forceinline__ void btf4i(float2& x0, float2& x1, float2& x2,
                                      float2& x3, float2 w1, float2 w2,
                                      float2 w3) {
  float2 b1 = cmulc(x1, w1), b2 = cmulc(x2, w2), b3 = cmulc(x3, w3);
  float2 A = cadd(x0, b2), B = csub(x0, b2);
  float2 C = cadd(b1, b3), D = csub(b1, b3);
  x0 = cadd(A, C);
  x1 = make_float2(B.x - D.y, B.y + D.x);      // B + iD
  x2 = csub(A, C);
  x3 = make_float2(B.x + D.y, B.y - D.x);      // B - iD
}
__device__ __forceinline__ int rev4(int p) {   // reverse 5 base-4 digits
  return ((p & 3) << 8) | (((p >> 2) & 3) << 6) | (((p >> 4) & 3) << 4) |
         (((p >> 6) & 3) << 2) | ((p >> 8) & 3);
}

// ---------------------------------------------------------------------------
// Kernel A: FFT correlation partials + tf row-norms fused.
// grid = 512 blocks (bh = blk&31, g4 = blk>>5) x 512 threads.
// Each half-block (256 lanes) runs a full packed radix-4 FFT correlation for
// channel-pair p = g4*2 + hb and writes PLAIN partials amp_part[p][bh][t]
// (no atomics -> no zeroing, no cross-XCD atomic serialization).
// Twiddles computed in-kernel (2 sincosf/thread). Block also computes the
// tf_queries row-norms for its 64 rows (l = g4*64 .. +63).
// ---------------------------------------------------------------------------
__global__ __launch_bounds__(512) void fft_norm_kernel(
    const float* __restrict__ qm, const float* __restrict__ km,
    const float* __restrict__ tfq,
    float* __restrict__ amp_part, float* __restrict__ norms) {
  const int tid  = threadIdx.x;
  const int hb   = tid >> 8;          // half-block 0/1
  const int ltid = tid & 255;
  const int bh = blockIdx.x & 31;
  const int g4 = blockIdx.x >> 5;     // 0..15
  const int b = bh >> 3, h = bh & 7;

  __shared__ float2 zz[2][2][1088];   // [half][array] 34.8 KB
  __shared__ float2 tw[1024];         // 8 KB

  // twiddles exp(-2*pi*i*j/1024)
  for (int j = tid; j < 1024; j += 512) {
    float sn, cs;
    sincosf(6.283185307179586f * (float)j * (1.0f / 1024.0f), &sn, &cs);
    tw[j] = make_float2(cs, -sn);
  }

  // tf row-norms for rows l = g4*64 + r (64 rows, 16 lanes each, 2 slots/thr)
#pragma unroll
  for (int s2 = 0; s2 < 2; ++s2) {
    int slot = tid + (s2 << 9);       // 0..1023
    int r = slot >> 4, le = slot & 15;
    int l = (g4 << 6) + r;
    const float* row = tfq + ((size_t)(b * LSEQ + l) * NH + h) * NE;
    float4 v = *(const float4*)(row + (le << 2));
    float s = v.x * v.x + v.y * v.y + v.z * v.z + v.w * v.w;
#pragma unroll
    for (int off = 8; off > 0; off >>= 1) s += __shfl_xor(s, off, 16);
    if (le == 0) norms[(size_t)bh * LSEQ + l] = s;
  }

  // ---- packed FFT for channel pair p = g4*2 + hb ----
  const int pair = (g4 << 1) + hb;
  const size_t base =
      (size_t)b * (LSEQ * NH * NE) + (size_t)h * NE + (pair << 1);
  float2* z0 = zz[hb][0];
  float2* z1 = zz[hb][1];

  float2 a0[4], a1[4];
#pragma unroll
  for (int j = 0; j < 4; ++j) {
    int t = ltid + (j << 8);
    float2 qv = *(const float2*)(qm + base + (size_t)t * (NH * NE));
    float2 kv = *(const float2*)(km + base + (size_t)t * (NH * NE));
    a0[j] = make_float2(qv.x, kv.x);
    a1[j] = make_float2(qv.y, kv.y);
  }
  __syncthreads();   // tw ready

  // forward stage 1 (S=1024) in registers
  {
    float2 w1 = tw[ltid], w2 = tw[2 * ltid], w3 = tw[3 * ltid];
    btf4f(a0[0], a0[1], a0[2], a0[3], w1, w2, w3);
    btf4f(a1[0], a1[1], a1[2], a1[3], w1, w2, w3);
  }
#pragma unroll
  for (int j = 0; j < 4; ++j) {
    int t = ltid + (j << 8);
    z0[ZP(t)] = a0[j];
    z1[ZP(t)] = a1[j];
  }
  __syncthreads();

  // forward LDS stages: S = 256, 64, 16, 4
#pragma unroll
  for (int st = 0; st < 4; ++st) {
    const int l2h = 6 - 2 * st, l2S = 8 - 2 * st, sc = 2 + 2 * st;
    const int hh = 1 << l2h;
    const int q = ltid & (hh - 1);
    const int idx = ((ltid >> l2h) << l2S) + q;
    const int e1 = q << sc;
    float2 w1 = tw[e1], w2 = tw[2 * e1], w3 = tw[3 * e1];
    int i0 = ZP(idx), i1 = ZP(idx + hh), i2 = ZP(idx + 2 * hh),
        i3 = ZP(idx + 3 * hh);
    float2 x0 = z0[i0], x1 = z0[i1], x2 = z0[i2], x3 = z0[i3];
    btf4f(x0, x1, x2, x3, w1, w2, w3);
    z0[i0] = x0; z0[i1] = x1; z0[i2] = x2; z0[i3] = x3;
    x0 = z1[i0]; x1 = z1[i1]; x2 = z1[i2]; x3 = z1[i3];
    btf4f(x0, x1, x2, x3, w1, w2, w3);
    z1[i0] = x0; z1[i1] = x1; z1[i2] = x2; z1[i3] = x3;
    __syncthreads();
  }

  // pointwise: P = Q*conj(K) per channel; pack Y = P0 + i*P1 (digit-rev dom.)
  float2 yv[4];
#pragma unroll
  for (int j = 0; j < 4; ++j) {
    int p = ltid + (j << 8);
    int f = rev4(p);
    int fm = (1024 - f) & 1023;
    int pm = rev4(fm);
    float2 A0 = z0[ZP(p)], B0 = z0[ZP(pm)];
    float2 A1 = z1[ZP(p)], B1 = z1[ZP(pm)];
    float2 Q0 = make_float2(0.5f * (A0.x + B0.x), 0.5f * (A0.y - B0.y));
    float2 iK0 = make_float2(0.5f * (A0.x - B0.x), 0.5f * (A0.y + B0.y));
    float2 K0 = make_float2(iK0.y, -iK0.x);
    float2 P0 = make_float2(Q0.x * K0.x + Q0.y * K0.y,
                            Q0.y * K0.x - Q0.x * K0.y);
    float2 Q1 = make_float2(0.5f * (A1.x + B1.x), 0.5f * (A1.y - B1.y));
    float2 iK1 = make_float2(0.5f * (A1.x - B1.x), 0.5f * (A1.y + B1.y));
    float2 K1 = make_float2(iK1.y, -iK1.x);
    float2 P1 = make_float2(Q1.x * K1.x + Q1.y * K1.y,
                            Q1.y * K1.x - Q1.x * K1.y);
    yv[j] = make_float2(P0.x - P1.y, P0.y + P1.x);
  }
  __syncthreads();
#pragma unroll
  for (int j = 0; j < 4; ++j) z0[ZP(ltid + (j << 8))] = yv[j];
  __syncthreads();

  // inverse LDS stages: S = 4, 16, 64, 256
#pragma unroll
  for (int st = 0; st < 4; ++st) {
    const int l2h = 2 * st, l2S = 2 * st + 2, sc = 8 - 2 * st;
    const int hh = 1 << l2h;
    const int q = ltid & (hh - 1);
    const int idx = ((ltid >> l2h) << l2S) + q;
    const int e1 = q << sc;
    float2 w1 = tw[e1], w2 = tw[2 * e1], w3 = tw[3 * e1];
    int i0 = ZP(idx), i1 = ZP(idx + hh), i2 = ZP(idx + 2 * hh),
        i3 = ZP(idx + 3 * hh);
    float2 x0 = z0[i0], x1 = z0[i1], x2 = z0[i2], x3 = z0[i3];
    btf4i(x0, x1, x2, x3, w1, w2, w3);
    z0[i0] = x0; z0[i1] = x1; z0[i2] = x2; z0[i3] = x3;
    __syncthreads();
  }

  // final inverse stage (S=1024) in registers, then |y|^2 -> plain store
#pragma unroll
  for (int j = 0; j < 4; ++j) a0[j] = z0[ZP(ltid + (j << 8))];
  {
    float2 w1 = tw[ltid], w2 = tw[2 * ltid], w3 = tw[3 * ltid];
    btf4i(a0[0], a0[1], a0[2], a0[3], w1, w2, w3);
  }
  const float inv = 1.0f / 1024.0f;
  float* pp = amp_part + ((size_t)pair * 32 + bh) * LSEQ;
#pragma unroll
  for (int j = 0; j < 4; ++j) {
    int t = ltid + (j << 8);
    float2 y = a0[j];
    pp[t] = (y.x * y.x + y.y * y.y) * inv * inv;
  }
}

// ---------------------------------------------------------------------------
// Kernel B: top-35 per (bh, branch). Branch 0 sums the 32 FFT partials;
// branch 1 reads precomputed norms. u64 keys reproduce lax.top_k tie-break.
// ---------------------------------------------------------------------------
__global__ __launch_bounds__(256) void topk_kernel(
    const float* __restrict__ amp_part, const float* __restrict__ norms,
    int* __restrict__ sel_t, int* __restrict__ sel_tf) {
  __shared__ u64 cand[4 * NTOP];
  const int tid = threadIdx.x;
  const int bh = blockIdx.x & 31;
  const int arr = blockIdx.x >> 5;
  int* sel = (arr == 0 ? sel_t : sel_tf) + bh * NTOP;

  const int wid = tid >> 6, lane = tid & 63;
  const int kb = wid << 8;
  u64 k0, k1, k2, k3;
  if (arr == 0) {
    float a[4] = {0.f, 0.f, 0.f, 0.f};
    for (int p = 0; p < 32; ++p) {
      const float* pp = amp_part + ((size_t)p * 32 + bh) * LSEQ + kb + lane;
#pragma unroll
      for (int j = 0; j < 4; ++j) a[j] += pp[j << 6];
    }
    k0 = ((u64)__float_as_uint(a[0]) << 32) | (unsigned)(LSEQ - 1 - (kb + lane));
    k1 = ((u64)__float_as_uint(a[1]) << 32) | (unsigned)(LSEQ - 1 - (kb + 64 + lane));
    k2 = ((u64)__float_as_uint(a[2]) << 32) | (unsigned)(LSEQ - 1 - (kb + 128 + lane));
    k3 = ((u64)__float_as_uint(a[3]) << 32) | (unsigned)(LSEQ - 1 - (kb + 192 + lane));
  } else {
    const float* sc = norms + (size_t)bh * LSEQ;
    int l;
    l = kb + lane;
    k0 = ((u64)__float_as_uint(sc[l]) << 32) | (unsigned)(LSEQ - 1 - l);
    l = kb + 64 + lane;
    k1 = ((u64)__float_as_uint(sc[l]) << 32) | (unsigned)(LSEQ - 1 - l);
    l = kb + 128 + lane;
    k2 = ((u64)__float_as_uint(sc[l]) << 32) | (unsigned)(LSEQ - 1 - l);
    l = kb + 192 + lane;
    k3 = ((u64)__float_as_uint(sc[l]) << 32) | (unsigned)(LSEQ - 1 - l);
  }
  for (int it = 0; it < NTOP; ++it) {
    u64 m01 = k0 > k1 ? k0 : k1;
    u64 m23 = k2 > k3 ? k2 : k3;
    u64 m = m01 > m23 ? m01 : m23;
#pragma unroll
    for (int off = 32; off > 0; off >>= 1) {
      u64 o = __shfl_xor(m, off);
      m = o > m ? o : m;
    }
    if (k0 == m) k0 = 0;
    else if (k1 == m) k1 = 0;
    else if (k2 == m) k2 = 0;
    else if (k3 == m) k3 = 0;
    if (lane == 0) cand[wid * NTOP + it] = m;
  }
  __syncthreads();

  if (tid < 64) {
    u64 c0 = (tid < 4 * NTOP) ? cand[tid] : 0;
    u64 c1 = (tid + 64 < 4 * NTOP) ? cand[tid + 64] : 0;
    u64 c2 = (tid + 128 < 4 * NTOP) ? cand[tid + 128] : 0;
    for (int it = 0; it < NTOP; ++it) {
      u64 m01 = c0 > c1 ? c0 : c1;
      u64 m = m01 > c2 ? m01 : c2;
#pragma unroll
      for (int off = 32; off > 0; off >>= 1) {
        u64 o = __shfl_xor(m, off);
        m = o > m ? o : m;
      }
      if (c0 == m) c0 = 0;
      else if (c1 == m) c1 = 0;
      else if (c2 == m) c2 = 0;
      if (tid == 0) sel[it] = (LSEQ - 1) - (int)(m & 0xffffffffULL);
    }
  }
}

// ---------------------------------------------------------------------------
// Kernel C v5: two-GEMM attention tail, 512 threads (8 waves = 2/SIMD).
// Score GEMM: 16 strips x 5 rows, 32 key-groups x 4 keys.
// PV GEMM: 16 d-groups x 4d, 32 key-groups x 4k.
// ---------------------------------------------------------------------------
__global__ __launch_bounds__(512) void attn_out_kernel(
    const float* __restrict__ qm, const float* __restrict__ tfq,
    const float* __restrict__ km, const float* __restrict__ vm,
    const float* __restrict__ mixw,
    const int* __restrict__ sel_t, const int* __restrict__ sel_tf,
    float* __restrict__ out) {
  __shared__ float Qs[2 * 40 * 68];    // 21.3 KB  [gr][68]
  __shared__ float Xs[2 * 64 * 132];   // 66.0 KB  [br][e][132]
  __shared__ float Ss[2 * 40 * 132];   // 41.3 KB  [gr][132]
  __shared__ float Vs[2 * 36 * 68];    // 19.1 KB

  const int tid = threadIdx.x;
  const int kc = blockIdx.x & 7;
  const int bh = blockIdx.x >> 3;
  const int b = bh >> 3, h = bh & 7;
  const int k0 = kc << 7;
  const size_t base = (size_t)b * (LSEQ * NH * NE) + (size_t)h * NE;

  // ---- stage Q (80 rows: br0 0..39, br1 40..79; rows >=35 per br zeroed) ----
  for (int i = tid; i < 1280; i += 512) {
    int r = i >> 4, e4 = (i & 15) << 2;
    int br = (r >= 40), n = r - (br ? 40 : 0);
    float4 v = make_float4(0.f, 0.f, 0.f, 0.f);
    if (n < NTOP) {
      int l = (br ? sel_tf : sel_t)[bh * NTOP + n];
      v = *(const float4*)((br ? tfq : qm) + base + (size_t)l * (NH * NE) + e4);
    }
    *(float4*)&Qs[r * 68 + e4] = v;
  }
  // ---- stage V ----
  for (int i = tid; i < 1152; i += 512) {
    int r = i >> 4, e4 = (i & 15) << 2;
    int br = (r >= 36), n = r - (br ? 36 : 0);
    float4 v = make_float4(0.f, 0.f, 0.f, 0.f);
    if (n < NTOP) {
      int l = (br ? sel_tf : sel_t)[bh * NTOP + n];
      v = *(const float4*)(vm + base + (size_t)l * (NH * NE) + e4);
    }
    *(float4*)&Vs[r * 68 + e4] = v;
  }
  // ---- stage X transposed, both branches ----
  for (int i = tid; i < 4096; i += 512) {
    int br = i >> 11, k = (i >> 4) & 127, e4 = (i & 15) << 2;
    const float* xsrc = br ? tfq : km;
    float4 v = *(const float4*)(xsrc + base + (size_t)(k0 + k) * (NH * NE) + e4);
    float* X = Xs + br * (64 * 132);
    X[(e4 + 0) * 132 + k] = v.x;
    X[(e4 + 1) * 132 + k] = v.y;
    X[(e4 + 2) * 132 + k] = v.z;
    X[(e4 + 3) * 132 + k] = v.w;
  }
  __syncthreads();

  // ---- score GEMM: strip s = tid>>5 (5 rows), 4 keys ----
  {
    const int s = tid >> 5;            // 0..15 (0-7 br0, 8-15 br1)
    const int kq4 = (tid & 31) << 2;   // 0..124
    const float* Xb = Xs + (s >> 3) * (64 * 132);
    float4 acc[5];
#pragma unroll
    for (int r = 0; r < 5; ++r) acc[r] = make_float4(0.f, 0.f, 0.f, 0.f);
    for (int e0 = 0; e0 < NE; e0 += 4) {
      float4 xv0 = *(const float4*)&Xb[(e0 + 0) * 132 + kq4];
      float4 xv1 = *(const float4*)&Xb[(e0 + 1) * 132 + kq4];
      float4 xv2 = *(const float4*)&Xb[(e0 + 2) * 132 + kq4];
      float4 xv3 = *(const float4*)&Xb[(e0 + 3) * 132 + kq4];
#pragma unroll
      for (int r = 0; r < 5; ++r) {
        float4 qv = *(const float4*)&Qs[(s * 5 + r) * 68 + e0];
        FMA4(acc[r], xv0, qv.x);
        FMA4(acc[r], xv1, qv.y);
        FMA4(acc[r], xv2, qv.z);
        FMA4(acc[r], xv3, qv.w);
      }
    }
#pragma unroll
    for (int r = 0; r < 5; ++r)
      *(float4*)&Ss[(s * 5 + r) * 132 + kq4] = acc[r];
  }
  __syncthreads();

  // ---- per-key softmax over 35 rows + mix coefficient (both branches) ----
  if (tid < 256) {
    const int k = tid & 127, br = tid >> 7;
    float p[NTOP];
    float mx = -1e30f;
#pragma unroll
    for (int n = 0; n < NTOP; ++n) {
      p[n] = Ss[(br * 40 + n) * 132 + k] * QKSCALE;
      mx = fmaxf(mx, p[n]);
    }
    float sum = 0.f;
#pragma unroll
    for (int n = 0; n < NTOP; ++n) { p[n] = __expf(p[n] - mx); sum += p[n]; }
    const float w0 = mixw[(size_t)h * (LSEQ * 2) + (size_t)(k0 + k) * 2 + 0];
    const float w1 = mixw[(size_t)h * (LSEQ * 2) + (size_t)(k0 + k) * 2 + 1];
    const float ew0 = __expf(w0), ew1 = __expf(w1);
    const float c = (br ? ew1 : ew0) / ((ew0 + ew1) * sum);
#pragma unroll
    for (int n = 0; n < NTOP; ++n) Ss[(br * 40 + n) * 132 + k] = p[n] * c;
  }
  __syncthreads();

  // ---- PV GEMM: 4d x 4k per thread, both branches accumulated ----
  {
    const int kq4 = (tid & 31) << 2;   // 4 keys
    const int d0 = (tid >> 5) << 2;    // 4 d
    float4 a[4];
#pragma unroll
    for (int dj = 0; dj < 4; ++dj) a[dj] = make_float4(0.f, 0.f, 0.f, 0.f);
#pragma unroll 5
    for (int n = 0; n < NTOP; ++n) {
      float4 p0 = *(const float4*)&Ss[n * 132 + kq4];
      float4 vv = *(const float4*)&Vs[n * 68 + d0];
      FMA4(a[0], p0, vv.x);
      FMA4(a[1], p0, vv.y);
      FMA4(a[2], p0, vv.z);
      FMA4(a[3], p0, vv.w);
    }
#pragma unroll 5
    for (int n = 0; n < NTOP; ++n) {
      float4 p1 = *(const float4*)&Ss[(40 + n) * 132 + kq4];
      float4 vv = *(const float4*)&Vs[(36 + n) * 68 + d0];
      FMA4(a[0], p1, vv.x);
      FMA4(a[1], p1, vv.y);
      FMA4(a[2], p1, vv.z);
      FMA4(a[3], p1, vv.w);
    }
    float* ob = out + (size_t)bh * (NE * LSEQ) + k0 + kq4;
#pragma unroll
    for (int dj = 0; dj < 4; ++dj)
      *(float4*)&ob[(size_t)(d0 + dj) * LSEQ] = a[dj];
  }
}

// ---------------------------------------------------------------------------
extern "C" void kernel_launch(void* const* d_in, const int* in_sizes, int n_in,
                              void* d_out, int out_size, void* d_ws, size_t ws_size,
                              hipStream_t stream) {
  const float* tfq  = (const float*)d_in[0];
  const float* qm   = (const float*)d_in[1];
  const float* km   = (const float*)d_in[2];
  const float* vm   = (const float*)d_in[3];
  const float* mixw = (const float*)d_in[6];
  // d_in[4], d_in[5] (weights1_*), d_in[7] (mask), d_in[8] (mode_index):
  // dead code w.r.t. the returned output — skipped.

  float* amp_part = (float*)d_ws;                     // 32*32*1024 f32 (4 MB)
  float* norms    = amp_part + 32 * 32 * LSEQ;        // 32*1024 f32
  int*   sel_t    = (int*)(norms + 32 * LSEQ);        // 32*35 i32
  int*   sel_tf   = sel_t + 32 * NTOP;
  float* out      = (float*)d_out;

  fft_norm_kernel<<<dim3(512), dim3(512), 0, stream>>>(qm, km, tfq,
                                                       amp_part, norms);
  topk_kernel<<<dim3(64), dim3(256), 0, stream>>>(amp_part, norms,
                                                  sel_t, sel_tf);
  attn_out_kernel<<<dim3(256), dim3(512), 0, stream>>>(qm, tfq, km, vm, mixw,
                                                       sel_t, sel_tf, out);
}